// Round 7
// baseline (650.888 us; speedup 1.0000x reference)
//
#include <hip/hip_runtime.h>
#include <hip/hip_bf16.h>
#include <math.h>

// Transformer: L=4, D=512, NH=8, DH=64, DFF=2048, Tp=1024, B=4
// x layout: (Tp, B, D) rows: row = i*B + b, M = 4096.

#define TP 1024
#define BB 4
#define DD 512
#define DHEAD 64
#define DFF 2048
#define MROWS (TP*BB)   // 4096
#define EPS 1e-5f
#define CSC 0.18033688011112042f   // 0.125 * log2(e)

typedef __attribute__((ext_vector_type(8))) short bf16x8;
typedef __attribute__((ext_vector_type(4))) float f32x4;

__device__ __forceinline__ float b2f(unsigned short u) {
    union { unsigned int i; float f; } z; z.i = ((unsigned int)u) << 16; return z.f;
}
__device__ __forceinline__ unsigned short f2bu(float f) {
    __hip_bfloat16 h = __float2bfloat16(f);
    return *reinterpret_cast<unsigned short*>(&h);
}

#define WAITV0() asm volatile("s_waitcnt vmcnt(0)" ::: "memory")
#define WAITV4() asm volatile("s_waitcnt vmcnt(4)" ::: "memory")
#define WAITV8() asm volatile("s_waitcnt vmcnt(8)" ::: "memory")
#define WAITL0() asm volatile("s_waitcnt lgkmcnt(0)" ::: "memory")
__device__ __forceinline__ void hard_barrier() {
    __builtin_amdgcn_sched_barrier(0);
    __builtin_amdgcn_s_barrier();
    __builtin_amdgcn_sched_barrier(0);
}
#define GLOAD(gp, lp) __builtin_amdgcn_global_load_lds( \
    (const __attribute__((address_space(1))) void*)(gp), \
    (__attribute__((address_space(3))) void*)(lp), 16, 0, 0)

// LDS slot swizzle for [rows][32 bf16] tiles (64B rows, 4x16B slots/row).
// slot' = slot ^ fsw(row) gives perfect 2-way bank aliasing (free) for
// ds_read_b128 at 16 consecutive rows x fixed slot.
__device__ __forceinline__ int fsw(int row) { return (row ^ (row >> 2)) & 3; }

// ---------------- embed (coalesced via LDS transpose) ----------------------
// grid 512 = (t 16) x (b 4) x (dc 8); each block: 64 d x 64 hw tile.
__global__ __launch_bounds__(256) void embed_kernel(const float* __restrict__ z,
                                                    float* __restrict__ x,
                                                    __hip_bfloat16* __restrict__ x_bf) {
    __shared__ float tile[64][65];
    const int blk = blockIdx.x;
    const int dc = blk & 7, b = (blk >> 3) & 3, t = blk >> 5;
    const int tid = threadIdx.x;
#pragma unroll
    for (int it = 0; it < 4; ++it) {
        int idx = it * 256 + tid;
        int d_i = idx >> 4, hw4 = (idx & 15) * 4;
        int d = dc * 64 + d_i;
        float4 v = *reinterpret_cast<const float4*>(
            z + ((size_t)((b * 16 + t) * 512 + d)) * 64 + hw4);
        int j = d & 255;
        float freq = expf(-(float)(2 * j) * (9.210340371976184f / 512.0f));
        int i0 = t * 64 + hw4;
#pragma unroll
        for (int e = 0; e < 4; ++e) {
            float si = (float)(i0 + e) * freq;
            float pe = (d < 256) ? sinf(si) : cosf(si);
            tile[d_i][hw4 + e] = ((&v.x)[e]) + pe;
        }
    }
    __syncthreads();
#pragma unroll
    for (int it = 0; it < 4; ++it) {
        int idx = it * 256 + tid;
        int hw_o = idx >> 4, dq = (idx & 15) * 4;
        int row = (t * 64 + hw_o) * 4 + b;
        float4 v = make_float4(tile[dq][hw_o], tile[dq + 1][hw_o],
                               tile[dq + 2][hw_o], tile[dq + 3][hw_o]);
        *reinterpret_cast<float4*>(x + (size_t)row * 512 + dc * 64 + dq) = v;
        ushort4 u;
        u.x = f2bu(v.x); u.y = f2bu(v.y); u.z = f2bu(v.z); u.w = f2bu(v.w);
        *reinterpret_cast<ushort4*>((unsigned short*)x_bf + (size_t)row * 512 + dc * 64 + dq) = u;
    }
}

// ---------------- weight transpose+convert, ALL layers in one dispatch -----
__global__ __launch_bounds__(256) void wt_convert(
    const float* __restrict__ Wq, const float* __restrict__ Wk,
    const float* __restrict__ Wv, const float* __restrict__ Wo,
    const float* __restrict__ W1, const float* __restrict__ W2,
    __hip_bfloat16* __restrict__ wall) {
    __shared__ float tile[32][33];
    const int l = blockIdx.y;
    __hip_bfloat16* wl = wall + (size_t)l * (4 * 512 * 512 + 2 * 512 * 2048);
    int b = blockIdx.x;
    const float* src; __hip_bfloat16* dst; int R, C, local, cbs;
    if (b < 1024) {
        int m = b >> 8; local = b & 255; R = 512; C = 512; cbs = 4;
        src = ((m == 0) ? Wq : (m == 1) ? Wk : (m == 2) ? Wv : Wo) + (size_t)l * 512 * 512;
        dst = wl + m * 512 * 512;
    } else if (b < 2048) {
        local = b - 1024; R = 512; C = 2048; cbs = 6;
        src = W1 + (size_t)l * 512 * 2048; dst = wl + 4 * 512 * 512;
    } else {
        local = b - 2048; R = 2048; C = 512; cbs = 4;
        src = W2 + (size_t)l * 2048 * 512; dst = wl + 4 * 512 * 512 + 512 * 2048;
    }
    int bx = local & ((1 << cbs) - 1), by = local >> cbs;
    int tx = threadIdx.x & 31, ty = threadIdx.x >> 5;
#pragma unroll
    for (int j = 0; j < 4; ++j)
        tile[ty + j * 8][tx] = src[(size_t)(by * 32 + ty + j * 8) * C + bx * 32 + tx];
    __syncthreads();
#pragma unroll
    for (int j = 0; j < 4; ++j)
        dst[(size_t)(bx * 32 + ty + j * 8) * R + by * 32 + tx] =
            __float2bfloat16(tile[tx][ty + j * 8]);
}

// ---------------- bf16 MFMA GEMM 128x128 (FF1): ring-2, swizzled LDS -------
template<bool BIAS, bool RELU, bool OUT_BF16>
__global__ __launch_bounds__(256) void gemm_k(const __hip_bfloat16* __restrict__ A,
                                              const __hip_bfloat16* __restrict__ Bt,
                                              const float* __restrict__ bias,
                                              void* __restrict__ Cout,
                                              int N, int K, int ntx) {
    __shared__ __hip_bfloat16 As[2][128 * 32];
    __shared__ __hip_bfloat16 Bs[2][128 * 32];

    const int lb = blockIdx.x;
    const int wg = (lb & 7) * (gridDim.x >> 3) + (lb >> 3);
    const int m0 = (wg / ntx) * 128;
    const int n0 = (wg % ntx) * 128;

    const int tid  = threadIdx.x;
    const int wave = tid >> 6;
    const int lane = tid & 63;
    const int lr   = lane & 15;
    const int hi   = lane >> 4;
    const int lk   = (hi ^ fsw(lr)) << 3;     // swizzled k-slot
    const int wr   = (wave >> 1) * 64;
    const int wc   = (wave & 1) * 64;

    f32x4 acc[4][4];
#pragma unroll
    for (int i = 0; i < 4; ++i)
#pragma unroll
        for (int j = 0; j < 4; ++j) acc[i][j] = (f32x4){0.f, 0.f, 0.f, 0.f};

    const int c0 = tid, c1 = tid + 256;
    // pre-swizzled global source: chunk c -> row c>>2, slot (c&3)^fsw(row)
    const __hip_bfloat16* a0 = A  + (size_t)(m0 + (c0 >> 2)) * K + (((c0 & 3) ^ fsw(c0 >> 2)) << 3);
    const __hip_bfloat16* a1 = A  + (size_t)(m0 + (c1 >> 2)) * K + (((c1 & 3) ^ fsw(c1 >> 2)) << 3);
    const __hip_bfloat16* b0 = Bt + (size_t)(n0 + (c0 >> 2)) * K + (((c0 & 3) ^ fsw(c0 >> 2)) << 3);
    const __hip_bfloat16* b1 = Bt + (size_t)(n0 + (c1 >> 2)) * K + (((c1 & 3) ^ fsw(c1 >> 2)) << 3);
    const int o0 = wave * 512, o1 = 2048 + wave * 512;

    GLOAD(a0, &As[0][o0]); GLOAD(a1, &As[0][o1]);
    GLOAD(b0, &Bs[0][o0]); GLOAD(b1, &Bs[0][o1]);
    WAITV0();
    hard_barrier();

    for (int k0 = 0; k0 < K; k0 += 32) {
        const int buf = (k0 >> 5) & 1;
        if (k0 + 32 < K) {
            GLOAD(a0 + k0 + 32, &As[buf ^ 1][o0]); GLOAD(a1 + k0 + 32, &As[buf ^ 1][o1]);
            GLOAD(b0 + k0 + 32, &Bs[buf ^ 1][o0]); GLOAD(b1 + k0 + 32, &Bs[buf ^ 1][o1]);
        }
        bf16x8 af[4], bfv[4];
#pragma unroll
        for (int i = 0; i < 4; ++i)
            af[i] = *reinterpret_cast<const bf16x8*>(&As[buf][(size_t)(wr + i * 16 + lr) * 32 + lk]);
#pragma unroll
        for (int j = 0; j < 4; ++j)
            bfv[j] = *reinterpret_cast<const bf16x8*>(&Bs[buf][(size_t)(wc + j * 16 + lr) * 32 + lk]);
#pragma unroll
        for (int i = 0; i < 4; ++i)
#pragma unroll
            for (int j = 0; j < 4; ++j)
                acc[i][j] = __builtin_amdgcn_mfma_f32_16x16x32_bf16(af[i], bfv[j], acc[i][j], 0, 0, 0);
        WAITV0();
        hard_barrier();
    }

#pragma unroll
    for (int j = 0; j < 4; ++j) {
        int col = n0 + wc + j * 16 + lr;
        float bv = BIAS ? bias[col] : 0.0f;
#pragma unroll
        for (int i = 0; i < 4; ++i) {
            int row = m0 + wr + i * 16 + (hi << 2);
#pragma unroll
            for (int r = 0; r < 4; ++r) {
                float v = acc[i][j][r] + bv;
                if (RELU) v = fmaxf(v, 0.0f);
                if (OUT_BF16)
                    ((unsigned short*)Cout)[(size_t)(row + r) * N + col] = f2bu(v);
                else
                    ((float*)Cout)[(size_t)(row + r) * N + col] = v;
            }
        }
    }
}

// ---------------- bf16 MFMA GEMM 64x64 (QKV): ring-2, swizzled LDS ---------
template<bool OUT_BF16>
__device__ __forceinline__ void gemm64_body(const __hip_bfloat16* __restrict__ A,
                                            const __hip_bfloat16* __restrict__ Bt,
                                            void* __restrict__ Cout, int K,
                                            float scale,
                                            __hip_bfloat16* As, __hip_bfloat16* Bs) {
    const int lb = blockIdx.x;
    const int wg = (lb & 7) * (gridDim.x >> 3) + (lb >> 3);
    const int m0 = (wg >> 3) * 64;
    const int n0 = (wg & 7) * 64;

    const int tid  = threadIdx.x;
    const int wave = tid >> 6;
    const int lane = tid & 63;
    const int lr   = lane & 15;
    const int hi   = lane >> 4;
    const int lk   = (hi ^ fsw(lr)) << 3;
    const int wr   = (wave >> 1) * 32;
    const int wc   = (wave & 1) * 32;

    f32x4 acc[2][2];
#pragma unroll
    for (int i = 0; i < 2; ++i)
#pragma unroll
        for (int j = 0; j < 2; ++j) acc[i][j] = (f32x4){0.f, 0.f, 0.f, 0.f};

    const __hip_bfloat16* ag = A  + (size_t)(m0 + (tid >> 2)) * K + (((tid & 3) ^ fsw(tid >> 2)) << 3);
    const __hip_bfloat16* bg = Bt + (size_t)(n0 + (tid >> 2)) * K + (((tid & 3) ^ fsw(tid >> 2)) << 3);
    const int wo = wave * 512;

    GLOAD(ag, As + wo); GLOAD(bg, Bs + wo);
    WAITV0();
    hard_barrier();

    for (int k0 = 0; k0 < K; k0 += 32) {
        const int buf = (k0 >> 5) & 1;
        if (k0 + 32 < K) {
            GLOAD(ag + k0 + 32, As + (buf ^ 1) * 2048 + wo);
            GLOAD(bg + k0 + 32, Bs + (buf ^ 1) * 2048 + wo);
        }
        const __hip_bfloat16* Ab = As + buf * 2048;
        const __hip_bfloat16* Bb = Bs + buf * 2048;
        bf16x8 af[2], bfv[2];
#pragma unroll
        for (int i = 0; i < 2; ++i)
            af[i] = *reinterpret_cast<const bf16x8*>(&Ab[(size_t)(wr + i * 16 + lr) * 32 + lk]);
#pragma unroll
        for (int j = 0; j < 2; ++j)
            bfv[j] = *reinterpret_cast<const bf16x8*>(&Bb[(size_t)(wc + j * 16 + lr) * 32 + lk]);
#pragma unroll
        for (int i = 0; i < 2; ++i)
#pragma unroll
            for (int j = 0; j < 2; ++j)
                acc[i][j] = __builtin_amdgcn_mfma_f32_16x16x32_bf16(af[i], bfv[j], acc[i][j], 0, 0, 0);
        WAITV0();
        hard_barrier();
    }

#pragma unroll
    for (int j = 0; j < 2; ++j) {
        int col = n0 + wc + j * 16 + lr;
#pragma unroll
        for (int i = 0; i < 2; ++i) {
            int row = m0 + wr + i * 16 + (hi << 2);
#pragma unroll
            for (int r = 0; r < 4; ++r) {
                float v = acc[i][j][r] * scale;
                if (OUT_BF16)
                    ((unsigned short*)Cout)[(size_t)(row + r) * 512 + col] = f2bu(v);
                else
                    ((float*)Cout)[(size_t)(row + r) * 512 + col] = v;
            }
        }
    }
}

__global__ __launch_bounds__(256) void gemm_qkv64(const __hip_bfloat16* __restrict__ A,
                                                  const __hip_bfloat16* __restrict__ B0,
                                                  const __hip_bfloat16* __restrict__ B1,
                                                  const __hip_bfloat16* __restrict__ B2,
                                                  __hip_bfloat16* __restrict__ C0,
                                                  __hip_bfloat16* __restrict__ C1,
                                                  __hip_bfloat16* __restrict__ C2) {
    __shared__ __hip_bfloat16 As[2 * 64 * 32];
    __shared__ __hip_bfloat16 Bs[2 * 64 * 32];
    int sel = blockIdx.z;
    const __hip_bfloat16* Bt = (sel == 0) ? B0 : (sel == 1) ? B1 : B2;
    __hip_bfloat16* C = (sel == 0) ? C0 : (sel == 1) ? C1 : C2;
    float scale = (sel == 0) ? CSC : 1.0f;   // fold 0.125*log2(e) into Q
    gemm64_body<true>(A, Bt, (void*)C, 512, scale, As, Bs);
}

// ---------------- fused GEMM + LayerNorm + residual ------------------------
// C16 = A[16 rows] @ Bt^T (full N=512) (+bias); x += LN(C16)*g+beta; writes
// x f32 + x_bf. 256 blocks x 256 thr; wave w owns cols w*128..w*128+127.
template<bool BIAS>
__global__ __launch_bounds__(256) void gemm_ln_k(const __hip_bfloat16* __restrict__ A,
                                                 const __hip_bfloat16* __restrict__ Bt,
                                                 const float* __restrict__ bias,
                                                 const float* __restrict__ g,
                                                 const float* __restrict__ beta,
                                                 float* __restrict__ x,
                                                 __hip_bfloat16* __restrict__ x_bf,
                                                 int K) {
    __shared__ __hip_bfloat16 As[2][16 * 32];
    __shared__ __hip_bfloat16 Bs[2][512 * 32];
    __shared__ float red[2][4][16];

    const int lb = blockIdx.x;
    const int wg = (lb & 7) * 32 + (lb >> 3);    // XCD swizzle, 256 blocks
    const int m0 = wg * 16;

    const int tid  = threadIdx.x;
    const int wave = tid >> 6;
    const int lane = tid & 63;
    const int lr   = lane & 15;
    const int hi   = lane >> 4;
    const int lk   = (hi ^ fsw(lr)) << 3;

    f32x4 acc[8];
#pragma unroll
    for (int j = 0; j < 8; ++j) acc[j] = (f32x4){0.f, 0.f, 0.f, 0.f};

    // B staging: 2048 chunks of 16B; thread handles c = it*256 + wave*64 + lane
    const __hip_bfloat16* bg[8];
#pragma unroll
    for (int it = 0; it < 8; ++it) {
        int c = it * 256 + tid;
        bg[it] = Bt + (size_t)(c >> 2) * K + (((c & 3) ^ fsw(c >> 2)) << 3);
    }
    // A staging: 64 chunks, wave 0 only
    const __hip_bfloat16* ag =
        A + (size_t)(m0 + (lane >> 2)) * K + (((lane & 3) ^ fsw(lane >> 2)) << 3);

#pragma unroll
    for (int it = 0; it < 8; ++it)
        GLOAD(bg[it], &Bs[0][(it * 256 + wave * 64) * 8]);
    if (wave == 0) GLOAD(ag, &As[0][0]);
    WAITV0();
    hard_barrier();

    for (int k0 = 0; k0 < K; k0 += 32) {
        const int buf = (k0 >> 5) & 1;
        if (k0 + 32 < K) {
#pragma unroll
            for (int it = 0; it < 8; ++it)
                GLOAD(bg[it] + k0 + 32, &Bs[buf ^ 1][(it * 256 + wave * 64) * 8]);
            if (wave == 0) GLOAD(ag + k0 + 32, &As[buf ^ 1][0]);
        }
        bf16x8 af = *reinterpret_cast<const bf16x8*>(&As[buf][(size_t)lr * 32 + lk]);
        __builtin_amdgcn_s_setprio(1);
#pragma unroll
        for (int j = 0; j < 8; ++j) {
            bf16x8 bf = *reinterpret_cast<const bf16x8*>(
                &Bs[buf][(size_t)(wave * 128 + j * 16 + lr) * 32 + lk]);
            acc[j] = __builtin_amdgcn_mfma_f32_16x16x32_bf16(af, bf, acc[j], 0, 0, 0);
        }
        __builtin_amdgcn_s_setprio(0);
        WAITV0();
        hard_barrier();
    }

    // add bias (pre-LN), per-row partial sums over this wave's 128 cols
    if (BIAS) {
#pragma unroll
        for (int j = 0; j < 8; ++j) {
            float bv = bias[wave * 128 + j * 16 + lr];
#pragma unroll
            for (int r = 0; r < 4; ++r) acc[j][r] += bv;
        }
    }
    float psum[4], psq[4];
#pragma unroll
    for (int r = 0; r < 4; ++r) {
        float s = 0.f, ss = 0.f;
#pragma unroll
        for (int j = 0; j < 8; ++j) { s += acc[j][r]; ss += acc[j][r] * acc[j][r]; }
#pragma unroll
        for (int off = 1; off < 16; off <<= 1) {
            s  += __shfl_xor(s, off);
            ss += __shfl_xor(ss, off);
        }
        psum[r] = s; psq[r] = ss;
    }
    if (lr == 0) {
#pragma unroll
        for (int r = 0; r < 4; ++r) {
            red[0][wave][hi * 4 + r] = psum[r];
            red[1][wave][hi * 4 + r] = psq[r];
        }
    }
    __syncthreads();
    float mean[4], rstd[4];
#pragma unroll
    for (int r = 0; r < 4; ++r) {
        int row = hi * 4 + r;
        float s  = red[0][0][row] + red[0][1][row] + red[0][2][row] + red[0][3][row];
        float ss = red[1][0][row] + red[1][1][row] + red[1][2][row] + red[1][3][row];
        float m = s * (1.0f / 512.0f);
        float v = ss * (1.0f / 512.0f) - m * m;
        mean[r] = m; rstd[r] = rsqrtf(v + EPS);
    }
#pragma unroll
    for (int j = 0; j < 8; ++j) {
        int col = wave * 128 + j * 16 + lr;
        float gv = g[col], bv = beta[col];
#pragma unroll
        for (int r = 0; r < 4; ++r) {
            size_t off = (size_t)(m0 + hi * 4 + r) * 512 + col;
            float xo = (acc[j][r] - mean[r]) * rstd[r] * gv + bv + x[off];
            x[off] = xo;
            ((unsigned short*)x_bf)[off] = f2bu(xo);
        }
    }
}

// ---------------- V transpose: v (tok,b,n,d) -> vt[bn][d][1024 keys] --------
__global__ __launch_bounds__(256) void transpose_v(const unsigned short* __restrict__ v,
                                                   unsigned short* __restrict__ vt) {
    __shared__ unsigned short t[64][72];
    const int kb = blockIdx.x;
    const int bn = blockIdx.y;
    const int b = bn >> 3, n = bn & 7;
    const int tid = threadIdx.x;
#pragma unroll
    for (int it = 0; it < 2; ++it) {
        int c = tid + it * 256;
        int row = c >> 3, d0 = (c & 7) * 8;
        const unsigned short* src =
            v + ((size_t)((kb * 64 + row) * 4 + b)) * 512 + n * 64 + d0;
        bf16x8 xv = *reinterpret_cast<const bf16x8*>(src);
#pragma unroll
        for (int e = 0; e < 8; ++e) t[row][d0 + e] = (unsigned short)xv[e];
    }
    __syncthreads();
#pragma unroll
    for (int it = 0; it < 2; ++it) {
        int c = tid + it * 256;
        int d = c >> 3, k0 = (c & 7) * 8;
        bf16x8 o;
#pragma unroll
        for (int e = 0; e < 8; ++e) o[e] = (short)t[k0 + e][d];
        *reinterpret_cast<bf16x8*>(vt + ((size_t)(bn * 64 + d)) * 1024 + kb * 64 + k0) = o;
    }
}

// ---------------- MFMA block-causal flash attention (flat softmax) ---------
__device__ __forceinline__ int aswz(int row, int col) {
    return (row * 64 + col) ^ ((row & 7) << 3);
}

__device__ __forceinline__ void stage_tile(const unsigned short* gbase, int stride,
                                           unsigned short* lds, int wave, int tid) {
#pragma unroll
    for (int it = 0; it < 2; ++it) {
        int c = tid + it * 256;
        int row = c >> 3;
        int i = (c & 7) ^ (row & 7);
        const unsigned short* g = gbase + (size_t)row * stride + i * 8;
        __builtin_amdgcn_global_load_lds(
            (const __attribute__((address_space(1))) void*)g,
            (__attribute__((address_space(3))) void*)(lds + it * 2048 + wave * 512),
            16, 0, 0);
    }
}

__global__ __launch_bounds__(256) void attn_mfma(const unsigned short* __restrict__ q,
                                                 const unsigned short* __restrict__ k,
                                                 const unsigned short* __restrict__ vt,
                                                 unsigned short* __restrict__ av) {
    __shared__ unsigned short Qs[64 * 64];
    __shared__ unsigned short Ks[4][64 * 64];
    __shared__ unsigned short Vts[4][64 * 64];
    __shared__ unsigned short Ps[64 * 64];

    const int tid = threadIdx.x;
    const int wave = tid >> 6, lane = tid & 63;
    const int lr = lane & 15, hi = lane >> 4;
    const int wr = wave * 16;

    const int p = blockIdx.x;            // XCD-affinity swizzle
    const int xcd = p & 7, idx = p >> 3;
    const int bn = xcd * 4 + (idx & 3);
    const int qb = 15 - (idx >> 2);      // long blocks first within XCD
    const int b = bn >> 3, n = bn & 7;

    const unsigned short* kcol  = k  + (size_t)b * 512 + n * 64;
    const unsigned short* vtrow = vt + (size_t)(bn * 64) * 1024;

    stage_tile(q + ((size_t)(qb * 64) * 4 + b) * 512 + n * 64, 2048, Qs, wave, tid);
    stage_tile(kcol, 2048, Ks[0], wave, tid);
    stage_tile(vtrow, 1024, Vts[0], wave, tid);
    if (qb >= 1) {
        stage_tile(kcol + (size_t)64 * 2048, 2048, Ks[1], wave, tid);
        stage_tile(vtrow + 64, 1024, Vts[1], wave, tid);
    }
    if (qb >= 2) {
        stage_tile(kcol + (size_t)128 * 2048, 2048, Ks[2], wave, tid);
        stage_tile(vtrow + 128, 1024, Vts[2], wave, tid);
    }

    f32x4 o_acc[4], l_acc;
#pragma unroll
    for (int db = 0; db < 4; ++db) o_acc[db] = (f32x4){0.f, 0.f, 0.f, 0.f};
    l_acc = (f32x4){0.f, 0.f, 0.f, 0.f};

    bf16x8 onesf;
#pragma unroll
    for (int e = 0; e < 8; ++e) onesf[e] = (short)0x3F80;   // bf16 1.0

    bf16x8 qf[2];

    for (int kb = 0; kb <= qb; ++kb) {
        const int ahead = (qb - kb >= 2) ? 2 : (qb - kb);
        if (ahead == 2) WAITV8();
        else if (ahead == 1) WAITV4();
        else WAITV0();
        hard_barrier();                  // stage(kb) fully in LDS for all waves
        if (kb + 3 <= qb) {
            stage_tile(kcol + (size_t)(kb + 3) * 64 * 2048, 2048,
                       Ks[(kb + 3) & 3], wave, tid);
            stage_tile(vtrow + (kb + 3) * 64, 1024, Vts[(kb + 3) & 3], wave, tid);
        }
        if (kb == 0) {
#pragma unroll
            for (int ks = 0; ks < 2; ++ks)
                qf[ks] = *reinterpret_cast<const bf16x8*>(
                    (const unsigned short*)Qs + aswz(wr + lr, ks * 32 + hi * 8));
        }
        const unsigned short* Kb = Ks[kb & 3];
        const unsigned short* Vb = Vts[kb & 3];

        f32x4 sf[4];
#pragma unroll
        for (int jb = 0; jb < 4; ++jb) sf[jb] = (f32x4){0.f, 0.f, 0.f, 0.f};
        __builtin_amdgcn_s_setprio(1);
#pragma unroll
        for (int ks = 0; ks < 2; ++ks) {
            bf16x8 a = qf[ks];
#pragma unroll
            for (int jb = 0; jb < 4; ++jb) {
                bf16x8 kf = *reinterpret_cast<const bf16x8*>(
                    Kb + aswz(jb * 16 + lr, ks * 32 + hi * 8));
                sf[jb] = __builtin_amdgcn_mfma_f32_16x16x32_bf16(a, kf, sf[jb], 0, 0, 0);
            }
        }
        __builtin_amdgcn_s_setprio(0);

        // flat softmax: p = exp2(min(s,100)); Q pre-scaled by 0.125*log2(e)
#pragma unroll
        for (int jb = 0; jb < 4; ++jb)
#pragma unroll
            for (int r = 0; r < 4; ++r) {
                float pe = exp2f(fminf(sf[jb][r], 100.0f));
                Ps[aswz(wr + 4 * hi + r, jb * 16 + lr)] = f2bu(pe);
            }
        WAITL0();
        hard_barrier();                  // P visible; vmcnt prefetch in flight

        __builtin_amdgcn_s_setprio(1);
#pragma unroll
        for (int ks = 0; ks < 2; ++ks) {
            bf16x8 pf = *reinterpret_cast<const bf16x8*>(
                (const unsigned short*)Ps + aswz(wr + lr, ks * 32 + hi * 8));
            l_acc = __builtin_amdgcn_mfma_f32_16x16x32_bf16(pf, onesf, l_acc, 0, 0, 0);
#pragma unroll
            for (int db = 0; db < 4; ++db) {
                bf16x8 vf = *reinterpret_cast<const bf16x8*>(
                    Vb + aswz(db * 16 + lr, ks * 32 + hi * 8));
                o_acc[db] = __builtin_amdgcn_mfma_f32_16x16x32_bf16(pf, vf, o_acc[db], 0, 0, 0);
            }
        }
        __builtin_amdgcn_s_setprio(0);
    }

#pragma unroll
    for (int r = 0; r < 4; ++r) {
        float inv = 1.0f / l_acc[r];
        int row = qb * 64 + wr + 4 * hi + r;
#pragma unroll
        for (int db = 0; db < 4; ++db)
            av[((size_t)row * 4 + b) * 512 + n * 64 + db * 16 + lr] =
                f2bu(o_acc[db][r] * inv);
    }
}

// ---------------- coalesced layer-output transpose: x -> out[b][t][l][d][hw]
__global__ __launch_bounds__(256) void out_transpose(const float* __restrict__ x,
                                                     float* __restrict__ out, int l) {
    __shared__ float tile[64][65];
    const int blk = blockIdx.x;          // 512 = t(16) * b(4) * dc(8)
    const int dc = blk & 7;
    const int b  = (blk >> 3) & 3;
    const int t  = blk >> 5;
    const int tid = threadIdx.x;
#pragma unroll
    for (int it = 0; it < 4; ++it) {
        int c = tid + it * 256;          // 0..1023
        int hw = c >> 4, f4 = c & 15;
        const float* src = x + (size_t)((t * 64 + hw) * 4 + b) * 512 + dc * 64 + f4 * 4;
        float4 v = *reinterpret_cast<const float4*>(src);
        tile[hw][f4 * 4 + 0] = v.x; tile[hw][f4 * 4 + 1] = v.y;
        tile[hw][f4 * 4 + 2] = v.z; tile[hw][f4 * 4 + 3] = v.w;
    }
    __syncthreads();
    size_t ob = (((size_t)(b * 16 + t) * 4 + l) * 512 + dc * 64) * 64;
#pragma unroll
    for (int it = 0; it < 4; ++it) {
        int c = tid + it * 256;
        int d = c >> 4, f4 = c & 15;
        float4 v = make_float4(tile[f4 * 4 + 0][d], tile[f4 * 4 + 1][d],
                               tile[f4 * 4 + 2][d], tile[f4 * 4 + 3][d]);
        *reinterpret_cast<float4*>(out + ob + (size_t)d * 64 + f4 * 4) = v;
    }
}

// ---------------- launcher ----------------
extern "C" void kernel_launch(void* const* d_in, const int* in_sizes, int n_in,
                              void* d_out, int out_size, void* d_ws, size_t ws_size,
                              hipStream_t stream) {
    const float* z    = (const float*)d_in[0];
    const float* Wq   = (const float*)d_in[1];
    const float* Wk   = (const float*)d_in[2];
    const float* Wv   = (const float*)d_in[3];
    const float* Wo   = (const float*)d_in[4];
    const float* W1   = (const float*)d_in[5];
    const float* b1   = (const float*)d_in[6];
    const float* W2   = (const float*)d_in[7];
    const float* b2   = (const float*)d_in[8];
    const float* ln1g = (const float*)d_in[9];
    const float* ln1b = (const float*)d_in[10];
    const float* ln2g = (const float*)d_in[11];
    const float* ln2b = (const float*)d_in[12];
    float* out = (float*)d_out;

    const size_t MB = 1u << 20;
    char* base = (char*)d_ws;
    float*          x     = (float*)(base);                       // 8 MB
    __hip_bfloat16* x_bf  = (__hip_bfloat16*)(base + 8  * MB);    // 4 MB
    __hip_bfloat16* q_bf  = (__hip_bfloat16*)(base + 12 * MB);    // 4 MB
    __hip_bfloat16* k_bf  = (__hip_bfloat16*)(base + 16 * MB);    // 4 MB
    __hip_bfloat16* v_bf  = (__hip_bfloat16*)(base + 20 * MB);    // 4 MB
    __hip_bfloat16* av_bf = (__hip_bfloat16*)(base + 24 * MB);    // 4 MB
    unsigned short* vt    = (unsigned short*)(base + 28 * MB);    // 4 MB
    __hip_bfloat16* wall  = (__hip_bfloat16*)(base + 36 * MB);    // 24 MB (4 layers)
    __hip_bfloat16* ff1_bf = q_bf;               // aliases q..av after attention

    const size_t WL = 4 * 512 * 512 + 2 * 512 * 2048;   // per-layer weight elems

    embed_kernel<<<512, 256, 0, stream>>>(z, x, x_bf);
    wt_convert<<<dim3(3072, 4), 256, 0, stream>>>(Wq, Wk, Wv, Wo, W1, W2, wall);

    for (int l = 0; l < 4; ++l) {
        __hip_bfloat16* wl  = wall + (size_t)l * WL;
        __hip_bfloat16* wqt = wl;
        __hip_bfloat16* wkt = wqt + 512 * 512;
        __hip_bfloat16* wvt = wkt + 512 * 512;
        __hip_bfloat16* wot = wvt + 512 * 512;
        __hip_bfloat16* w1t = wot + 512 * 512;     // [2048][512]
        __hip_bfloat16* w2t = w1t + 512 * 2048;    // [512][2048]

        gemm_qkv64<<<dim3(512, 1, 3), 256, 0, stream>>>(x_bf, wqt, wkt, wvt,
                                                        q_bf, k_bf, v_bf);

        transpose_v<<<dim3(16, 32), 256, 0, stream>>>((const unsigned short*)v_bf, vt);

        attn_mfma<<<512, 256, 0, stream>>>(
            (const unsigned short*)q_bf, (const unsigned short*)k_bf,
            vt, (unsigned short*)av_bf);

        gemm_ln_k<false><<<256, 256, 0, stream>>>(
            av_bf, wot, nullptr, ln1g + l * 512, ln1b + l * 512, x, x_bf, 512);

        gemm_k<true, true, true><<<512, 256, 0, stream>>>(
            x_bf, w1t, b1 + l * 2048, (void*)ff1_bf, 2048, 512, 16);

        gemm_ln_k<true><<<256, 256, 0, stream>>>(
            ff1_bf, w2t, b2 + l * 512, ln2g + l * 512, ln2b + l * 512, x, x_bf, 2048);

        out_transpose<<<512, 256, 0, stream>>>(x, out, l);
    }
}

// Round 8
// 465.190 us; speedup vs baseline: 1.3992x; 1.3992x over previous
//
#include <hip/hip_runtime.h>
#include <hip/hip_bf16.h>
#include <math.h>

// Transformer: L=4, D=512, NH=8, DH=64, DFF=2048, Tp=1024, B=4
// x layout: (Tp, B, D) rows: row = i*B + b, M = 4096.

#define TP 1024
#define BB 4
#define DD 512
#define DHEAD 64
#define DFF 2048
#define MROWS (TP*BB)   // 4096
#define EPS 1e-5f
#define CSC 0.18033688011112042f   // 0.125 * log2(e)

typedef __attribute__((ext_vector_type(8))) short bf16x8;
typedef __attribute__((ext_vector_type(4))) float f32x4;

__device__ __forceinline__ float b2f(unsigned short u) {
    union { unsigned int i; float f; } z; z.i = ((unsigned int)u) << 16; return z.f;
}
__device__ __forceinline__ unsigned short f2bu(float f) {
    __hip_bfloat16 h = __float2bfloat16(f);
    return *reinterpret_cast<unsigned short*>(&h);
}

#define WAITV0() asm volatile("s_waitcnt vmcnt(0)" ::: "memory")
#define WAITV4() asm volatile("s_waitcnt vmcnt(4)" ::: "memory")
#define WAITV8() asm volatile("s_waitcnt vmcnt(8)" ::: "memory")
#define WAITL0() asm volatile("s_waitcnt lgkmcnt(0)" ::: "memory")
__device__ __forceinline__ void hard_barrier() {
    __builtin_amdgcn_sched_barrier(0);
    __builtin_amdgcn_s_barrier();
    __builtin_amdgcn_sched_barrier(0);
}
#define GLOAD(gp, lp) __builtin_amdgcn_global_load_lds( \
    (const __attribute__((address_space(1))) void*)(gp), \
    (__attribute__((address_space(3))) void*)(lp), 16, 0, 0)

// LDS slot swizzle for [rows][32 bf16] tiles (64B rows, 4x16B slots/row).
__device__ __forceinline__ int fsw(int row) { return (row ^ (row >> 2)) & 3; }

// ---------------- embed (coalesced via LDS transpose) ----------------------
__global__ __launch_bounds__(256) void embed_kernel(const float* __restrict__ z,
                                                    float* __restrict__ x,
                                                    __hip_bfloat16* __restrict__ x_bf) {
    __shared__ float tile[64][65];
    const int blk = blockIdx.x;
    const int dc = blk & 7, b = (blk >> 3) & 3, t = blk >> 5;
    const int tid = threadIdx.x;
#pragma unroll
    for (int it = 0; it < 4; ++it) {
        int idx = it * 256 + tid;
        int d_i = idx >> 4, hw4 = (idx & 15) * 4;
        int d = dc * 64 + d_i;
        float4 v = *reinterpret_cast<const float4*>(
            z + ((size_t)((b * 16 + t) * 512 + d)) * 64 + hw4);
        int j = d & 255;
        float freq = expf(-(float)(2 * j) * (9.210340371976184f / 512.0f));
        int i0 = t * 64 + hw4;
#pragma unroll
        for (int e = 0; e < 4; ++e) {
            float si = (float)(i0 + e) * freq;
            float pe = (d < 256) ? sinf(si) : cosf(si);
            tile[d_i][hw4 + e] = ((&v.x)[e]) + pe;
        }
    }
    __syncthreads();
#pragma unroll
    for (int it = 0; it < 4; ++it) {
        int idx = it * 256 + tid;
        int hw_o = idx >> 4, dq = (idx & 15) * 4;
        int row = (t * 64 + hw_o) * 4 + b;
        float4 v = make_float4(tile[dq][hw_o], tile[dq + 1][hw_o],
                               tile[dq + 2][hw_o], tile[dq + 3][hw_o]);
        *reinterpret_cast<float4*>(x + (size_t)row * 512 + dc * 64 + dq) = v;
        ushort4 u;
        u.x = f2bu(v.x); u.y = f2bu(v.y); u.z = f2bu(v.z); u.w = f2bu(v.w);
        *reinterpret_cast<ushort4*>((unsigned short*)x_bf + (size_t)row * 512 + dc * 64 + dq) = u;
    }
}

// ---------------- weight transpose+convert, ALL layers in one dispatch -----
__global__ __launch_bounds__(256) void wt_convert(
    const float* __restrict__ Wq, const float* __restrict__ Wk,
    const float* __restrict__ Wv, const float* __restrict__ Wo,
    const float* __restrict__ W1, const float* __restrict__ W2,
    __hip_bfloat16* __restrict__ wall) {
    __shared__ float tile[32][33];
    const int l = blockIdx.y;
    __hip_bfloat16* wl = wall + (size_t)l * (4 * 512 * 512 + 2 * 512 * 2048);
    int b = blockIdx.x;
    const float* src; __hip_bfloat16* dst; int R, C, local, cbs;
    if (b < 1024) {
        int m = b >> 8; local = b & 255; R = 512; C = 512; cbs = 4;
        src = ((m == 0) ? Wq : (m == 1) ? Wk : (m == 2) ? Wv : Wo) + (size_t)l * 512 * 512;
        dst = wl + m * 512 * 512;
    } else if (b < 2048) {
        local = b - 1024; R = 512; C = 2048; cbs = 6;
        src = W1 + (size_t)l * 512 * 2048; dst = wl + 4 * 512 * 512;
    } else {
        local = b - 2048; R = 2048; C = 512; cbs = 4;
        src = W2 + (size_t)l * 2048 * 512; dst = wl + 4 * 512 * 512 + 512 * 2048;
    }
    int bx = local & ((1 << cbs) - 1), by = local >> cbs;
    int tx = threadIdx.x & 31, ty = threadIdx.x >> 5;
#pragma unroll
    for (int j = 0; j < 4; ++j)
        tile[ty + j * 8][tx] = src[(size_t)(by * 32 + ty + j * 8) * C + bx * 32 + tx];
    __syncthreads();
#pragma unroll
    for (int j = 0; j < 4; ++j)
        dst[(size_t)(bx * 32 + ty + j * 8) * R + by * 32 + tx] =
            __float2bfloat16(tile[tx][ty + j * 8]);
}

// ---------------- bf16 MFMA GEMM 128x128 (FF1): ring-2, swizzled LDS -------
template<bool BIAS, bool RELU, bool OUT_BF16>
__global__ __launch_bounds__(256) void gemm_k(const __hip_bfloat16* __restrict__ A,
                                              const __hip_bfloat16* __restrict__ Bt,
                                              const float* __restrict__ bias,
                                              void* __restrict__ Cout,
                                              int N, int K, int ntx) {
    __shared__ __hip_bfloat16 As[2][128 * 32];
    __shared__ __hip_bfloat16 Bs[2][128 * 32];

    const int lb = blockIdx.x;
    const int wg = (lb & 7) * (gridDim.x >> 3) + (lb >> 3);
    const int m0 = (wg / ntx) * 128;
    const int n0 = (wg % ntx) * 128;

    const int tid  = threadIdx.x;
    const int wave = tid >> 6;
    const int lane = tid & 63;
    const int lr   = lane & 15;
    const int hi   = lane >> 4;
    const int lk   = (hi ^ fsw(lr)) << 3;     // swizzled k-slot
    const int wr   = (wave >> 1) * 64;
    const int wc   = (wave & 1) * 64;

    f32x4 acc[4][4];
#pragma unroll
    for (int i = 0; i < 4; ++i)
#pragma unroll
        for (int j = 0; j < 4; ++j) acc[i][j] = (f32x4){0.f, 0.f, 0.f, 0.f};

    const int c0 = tid, c1 = tid + 256;
    const __hip_bfloat16* a0 = A  + (size_t)(m0 + (c0 >> 2)) * K + (((c0 & 3) ^ fsw(c0 >> 2)) << 3);
    const __hip_bfloat16* a1 = A  + (size_t)(m0 + (c1 >> 2)) * K + (((c1 & 3) ^ fsw(c1 >> 2)) << 3);
    const __hip_bfloat16* b0 = Bt + (size_t)(n0 + (c0 >> 2)) * K + (((c0 & 3) ^ fsw(c0 >> 2)) << 3);
    const __hip_bfloat16* b1 = Bt + (size_t)(n0 + (c1 >> 2)) * K + (((c1 & 3) ^ fsw(c1 >> 2)) << 3);
    const int o0 = wave * 512, o1 = 2048 + wave * 512;

    GLOAD(a0, &As[0][o0]); GLOAD(a1, &As[0][o1]);
    GLOAD(b0, &Bs[0][o0]); GLOAD(b1, &Bs[0][o1]);
    WAITV0();
    hard_barrier();

    for (int k0 = 0; k0 < K; k0 += 32) {
        const int buf = (k0 >> 5) & 1;
        if (k0 + 32 < K) {
            GLOAD(a0 + k0 + 32, &As[buf ^ 1][o0]); GLOAD(a1 + k0 + 32, &As[buf ^ 1][o1]);
            GLOAD(b0 + k0 + 32, &Bs[buf ^ 1][o0]); GLOAD(b1 + k0 + 32, &Bs[buf ^ 1][o1]);
        }
        bf16x8 af[4], bfv[4];
#pragma unroll
        for (int i = 0; i < 4; ++i)
            af[i] = *reinterpret_cast<const bf16x8*>(&As[buf][(size_t)(wr + i * 16 + lr) * 32 + lk]);
#pragma unroll
        for (int j = 0; j < 4; ++j)
            bfv[j] = *reinterpret_cast<const bf16x8*>(&Bs[buf][(size_t)(wc + j * 16 + lr) * 32 + lk]);
#pragma unroll
        for (int i = 0; i < 4; ++i)
#pragma unroll
            for (int j = 0; j < 4; ++j)
                acc[i][j] = __builtin_amdgcn_mfma_f32_16x16x32_bf16(af[i], bfv[j], acc[i][j], 0, 0, 0);
        WAITV0();
        hard_barrier();
    }

#pragma unroll
    for (int j = 0; j < 4; ++j) {
        int col = n0 + wc + j * 16 + lr;
        float bv = BIAS ? bias[col] : 0.0f;
#pragma unroll
        for (int i = 0; i < 4; ++i) {
            int row = m0 + wr + i * 16 + (hi << 2);
#pragma unroll
            for (int r = 0; r < 4; ++r) {
                float v = acc[i][j][r] + bv;
                if (RELU) v = fmaxf(v, 0.0f);
                if (OUT_BF16)
                    ((unsigned short*)Cout)[(size_t)(row + r) * N + col] = f2bu(v);
                else
                    ((float*)Cout)[(size_t)(row + r) * N + col] = v;
            }
        }
    }
}

// ---------------- bf16 MFMA GEMM 64x64 (N=512 shapes): ring-2, swizzled ----
template<bool BIAS, bool RELU, bool OUT_BF16>
__device__ __forceinline__ void gemm64_body(const __hip_bfloat16* __restrict__ A,
                                            const __hip_bfloat16* __restrict__ Bt,
                                            const float* __restrict__ bias,
                                            void* __restrict__ Cout, int K,
                                            float scale,
                                            __hip_bfloat16* As, __hip_bfloat16* Bs) {
    const int lb = blockIdx.x;
    const int wg = (lb & 7) * (gridDim.x >> 3) + (lb >> 3);
    const int m0 = (wg >> 3) * 64;
    const int n0 = (wg & 7) * 64;

    const int tid  = threadIdx.x;
    const int wave = tid >> 6;
    const int lane = tid & 63;
    const int lr   = lane & 15;
    const int hi   = lane >> 4;
    const int lk   = (hi ^ fsw(lr)) << 3;
    const int wr   = (wave >> 1) * 32;
    const int wc   = (wave & 1) * 32;

    f32x4 acc[2][2];
#pragma unroll
    for (int i = 0; i < 2; ++i)
#pragma unroll
        for (int j = 0; j < 2; ++j) acc[i][j] = (f32x4){0.f, 0.f, 0.f, 0.f};

    const __hip_bfloat16* ag = A  + (size_t)(m0 + (tid >> 2)) * K + (((tid & 3) ^ fsw(tid >> 2)) << 3);
    const __hip_bfloat16* bg = Bt + (size_t)(n0 + (tid >> 2)) * K + (((tid & 3) ^ fsw(tid >> 2)) << 3);
    const int wo = wave * 512;

    GLOAD(ag, As + wo); GLOAD(bg, Bs + wo);
    WAITV0();
    hard_barrier();

    for (int k0 = 0; k0 < K; k0 += 32) {
        const int buf = (k0 >> 5) & 1;
        if (k0 + 32 < K) {
            GLOAD(ag + k0 + 32, As + (buf ^ 1) * 2048 + wo);
            GLOAD(bg + k0 + 32, Bs + (buf ^ 1) * 2048 + wo);
        }
        const __hip_bfloat16* Ab = As + buf * 2048;
        const __hip_bfloat16* Bb = Bs + buf * 2048;
        bf16x8 af[2], bfv[2];
#pragma unroll
        for (int i = 0; i < 2; ++i)
            af[i] = *reinterpret_cast<const bf16x8*>(&Ab[(size_t)(wr + i * 16 + lr) * 32 + lk]);
#pragma unroll
        for (int j = 0; j < 2; ++j)
            bfv[j] = *reinterpret_cast<const bf16x8*>(&Bb[(size_t)(wc + j * 16 + lr) * 32 + lk]);
#pragma unroll
        for (int i = 0; i < 2; ++i)
#pragma unroll
            for (int j = 0; j < 2; ++j)
                acc[i][j] = __builtin_amdgcn_mfma_f32_16x16x32_bf16(af[i], bfv[j], acc[i][j], 0, 0, 0);
        WAITV0();
        hard_barrier();
    }

#pragma unroll
    for (int j = 0; j < 2; ++j) {
        int col = n0 + wc + j * 16 + lr;
        float bv = BIAS ? bias[col] : 0.0f;
#pragma unroll
        for (int i = 0; i < 2; ++i) {
            int row = m0 + wr + i * 16 + (hi << 2);
#pragma unroll
            for (int r = 0; r < 4; ++r) {
                float v = acc[i][j][r] * scale + bv;
                if (RELU) v = fmaxf(v, 0.0f);
                if (OUT_BF16)
                    ((unsigned short*)Cout)[(size_t)(row + r) * 512 + col] = f2bu(v);
                else
                    ((float*)Cout)[(size_t)(row + r) * 512 + col] = v;
            }
        }
    }
}

template<bool BIAS, bool RELU, bool OUT_BF16>
__global__ __launch_bounds__(256) void gemm64_k(const __hip_bfloat16* __restrict__ A,
                                                const __hip_bfloat16* __restrict__ Bt,
                                                const float* __restrict__ bias,
                                                void* __restrict__ Cout, int K) {
    __shared__ __hip_bfloat16 As[2 * 64 * 32];
    __shared__ __hip_bfloat16 Bs[2 * 64 * 32];
    gemm64_body<BIAS, RELU, OUT_BF16>(A, Bt, bias, Cout, K, 1.0f, As, Bs);
}

__global__ __launch_bounds__(256) void gemm_qkv64(const __hip_bfloat16* __restrict__ A,
                                                  const __hip_bfloat16* __restrict__ B0,
                                                  const __hip_bfloat16* __restrict__ B1,
                                                  const __hip_bfloat16* __restrict__ B2,
                                                  __hip_bfloat16* __restrict__ C0,
                                                  __hip_bfloat16* __restrict__ C1,
                                                  __hip_bfloat16* __restrict__ C2) {
    __shared__ __hip_bfloat16 As[2 * 64 * 32];
    __shared__ __hip_bfloat16 Bs[2 * 64 * 32];
    int sel = blockIdx.z;
    const __hip_bfloat16* Bt = (sel == 0) ? B0 : (sel == 1) ? B1 : B2;
    __hip_bfloat16* C = (sel == 0) ? C0 : (sel == 1) ? C1 : C2;
    float scale = (sel == 0) ? CSC : 1.0f;   // fold 0.125*log2(e) into Q
    gemm64_body<false, false, true>(A, Bt, nullptr, (void*)C, 512, scale, As, Bs);
}

// ---------------- V transpose: v (tok,b,n,d) -> vt[bn][d][1024 keys] --------
__global__ __launch_bounds__(256) void transpose_v(const unsigned short* __restrict__ v,
                                                   unsigned short* __restrict__ vt) {
    __shared__ unsigned short t[64][72];
    const int kb = blockIdx.x;
    const int bn = blockIdx.y;
    const int b = bn >> 3, n = bn & 7;
    const int tid = threadIdx.x;
#pragma unroll
    for (int it = 0; it < 2; ++it) {
        int c = tid + it * 256;
        int row = c >> 3, d0 = (c & 7) * 8;
        const unsigned short* src =
            v + ((size_t)((kb * 64 + row) * 4 + b)) * 512 + n * 64 + d0;
        bf16x8 xv = *reinterpret_cast<const bf16x8*>(src);
#pragma unroll
        for (int e = 0; e < 8; ++e) t[row][d0 + e] = (unsigned short)xv[e];
    }
    __syncthreads();
#pragma unroll
    for (int it = 0; it < 2; ++it) {
        int c = tid + it * 256;
        int d = c >> 3, k0 = (c & 7) * 8;
        bf16x8 o;
#pragma unroll
        for (int e = 0; e < 8; ++e) o[e] = (short)t[k0 + e][d];
        *reinterpret_cast<bf16x8*>(vt + ((size_t)(bn * 64 + d)) * 1024 + kb * 64 + k0) = o;
    }
}

// ---------------- MFMA block-causal flash attention (flat softmax) ---------
__device__ __forceinline__ int aswz(int row, int col) {
    return (row * 64 + col) ^ ((row & 7) << 3);
}

__device__ __forceinline__ void stage_tile(const unsigned short* gbase, int stride,
                                           unsigned short* lds, int wave, int tid) {
#pragma unroll
    for (int it = 0; it < 2; ++it) {
        int c = tid + it * 256;
        int row = c >> 3;
        int i = (c & 7) ^ (row & 7);
        const unsigned short* g = gbase + (size_t)row * stride + i * 8;
        __builtin_amdgcn_global_load_lds(
            (const __attribute__((address_space(1))) void*)g,
            (__attribute__((address_space(3))) void*)(lds + it * 2048 + wave * 512),
            16, 0, 0);
    }
}

__global__ __launch_bounds__(256) void attn_mfma(const unsigned short* __restrict__ q,
                                                 const unsigned short* __restrict__ k,
                                                 const unsigned short* __restrict__ vt,
                                                 unsigned short* __restrict__ av) {
    __shared__ unsigned short Qs[64 * 64];
    __shared__ unsigned short Ks[4][64 * 64];
    __shared__ unsigned short Vts[4][64 * 64];
    __shared__ unsigned short Ps[64 * 64];

    const int tid = threadIdx.x;
    const int wave = tid >> 6, lane = tid & 63;
    const int lr = lane & 15, hi = lane >> 4;
    const int wr = wave * 16;

    const int p = blockIdx.x;            // XCD-affinity swizzle
    const int xcd = p & 7, idx = p >> 3;
    const int bn = xcd * 4 + (idx & 3);
    const int qb = 15 - (idx >> 2);      // long blocks first within XCD
    const int b = bn >> 3, n = bn & 7;

    const unsigned short* kcol  = k  + (size_t)b * 512 + n * 64;
    const unsigned short* vtrow = vt + (size_t)(bn * 64) * 1024;

    stage_tile(q + ((size_t)(qb * 64) * 4 + b) * 512 + n * 64, 2048, Qs, wave, tid);
    stage_tile(kcol, 2048, Ks[0], wave, tid);
    stage_tile(vtrow, 1024, Vts[0], wave, tid);
    if (qb >= 1) {
        stage_tile(kcol + (size_t)64 * 2048, 2048, Ks[1], wave, tid);
        stage_tile(vtrow + 64, 1024, Vts[1], wave, tid);
    }
    if (qb >= 2) {
        stage_tile(kcol + (size_t)128 * 2048, 2048, Ks[2], wave, tid);
        stage_tile(vtrow + 128, 1024, Vts[2], wave, tid);
    }

    f32x4 o_acc[4], l_acc;
#pragma unroll
    for (int db = 0; db < 4; ++db) o_acc[db] = (f32x4){0.f, 0.f, 0.f, 0.f};
    l_acc = (f32x4){0.f, 0.f, 0.f, 0.f};

    bf16x8 onesf;
#pragma unroll
    for (int e = 0; e < 8; ++e) onesf[e] = (short)0x3F80;   // bf16 1.0

    bf16x8 qf[2];

    for (int kb = 0; kb <= qb; ++kb) {
        const int ahead = (qb - kb >= 2) ? 2 : (qb - kb);
        if (ahead == 2) WAITV8();
        else if (ahead == 1) WAITV4();
        else WAITV0();
        hard_barrier();                  // stage(kb) fully in LDS for all waves
        if (kb + 3 <= qb) {
            stage_tile(kcol + (size_t)(kb + 3) * 64 * 2048, 2048,
                       Ks[(kb + 3) & 3], wave, tid);
            stage_tile(vtrow + (kb + 3) * 64, 1024, Vts[(kb + 3) & 3], wave, tid);
        }
        if (kb == 0) {
#pragma unroll
            for (int ks = 0; ks < 2; ++ks)
                qf[ks] = *reinterpret_cast<const bf16x8*>(
                    (const unsigned short*)Qs + aswz(wr + lr, ks * 32 + hi * 8));
        }
        const unsigned short* Kb = Ks[kb & 3];
        const unsigned short* Vb = Vts[kb & 3];

        f32x4 sf[4];
#pragma unroll
        for (int jb = 0; jb < 4; ++jb) sf[jb] = (f32x4){0.f, 0.f, 0.f, 0.f};
        __builtin_amdgcn_s_setprio(1);
#pragma unroll
        for (int ks = 0; ks < 2; ++ks) {
            bf16x8 a = qf[ks];
#pragma unroll
            for (int jb = 0; jb < 4; ++jb) {
                bf16x8 kf = *reinterpret_cast<const bf16x8*>(
                    Kb + aswz(jb * 16 + lr, ks * 32 + hi * 8));
                sf[jb] = __builtin_amdgcn_mfma_f32_16x16x32_bf16(a, kf, sf[jb], 0, 0, 0);
            }
        }
        __builtin_amdgcn_s_setprio(0);

        // flat softmax: p = exp2(min(s,100)); Q pre-scaled by 0.125*log2(e)
#pragma unroll
        for (int jb = 0; jb < 4; ++jb)
#pragma unroll
            for (int r = 0; r < 4; ++r) {
                float pe = exp2f(fminf(sf[jb][r], 100.0f));
                Ps[aswz(wr + 4 * hi + r, jb * 16 + lr)] = f2bu(pe);
            }
        WAITL0();
        hard_barrier();                  // P visible; vmcnt prefetch in flight

        __builtin_amdgcn_s_setprio(1);
#pragma unroll
        for (int ks = 0; ks < 2; ++ks) {
            bf16x8 pf = *reinterpret_cast<const bf16x8*>(
                (const unsigned short*)Ps + aswz(wr + lr, ks * 32 + hi * 8));
            l_acc = __builtin_amdgcn_mfma_f32_16x16x32_bf16(pf, onesf, l_acc, 0, 0, 0);
#pragma unroll
            for (int db = 0; db < 4; ++db) {
                bf16x8 vf = *reinterpret_cast<const bf16x8*>(
                    Vb + aswz(db * 16 + lr, ks * 32 + hi * 8));
                o_acc[db] = __builtin_amdgcn_mfma_f32_16x16x32_bf16(pf, vf, o_acc[db], 0, 0, 0);
            }
        }
        __builtin_amdgcn_s_setprio(0);
    }

#pragma unroll
    for (int r = 0; r < 4; ++r) {
        float inv = 1.0f / l_acc[r];
        int row = qb * 64 + wr + 4 * hi + r;
#pragma unroll
        for (int db = 0; db < 4; ++db)
            av[((size_t)row * 4 + b) * 512 + n * 64 + db * 16 + lr] =
                f2bu(o_acc[db][r] * inv);
    }
}

// ---------------- LN(y)*g+b + x -> x (f32 + bf16) ------
__global__ __launch_bounds__(64) void add_ln_kernel(const float* __restrict__ y,
                                                    const float* __restrict__ g,
                                                    const float* __restrict__ bta,
                                                    float* __restrict__ x,
                                                    __hip_bfloat16* __restrict__ x_bf) {
    const int row = blockIdx.x;     // 0..4095
    const int tid = threadIdx.x;    // 0..63
    const float* yr = y + (size_t)row * DD;
    float4 v0 = *reinterpret_cast<const float4*>(&yr[tid * 4]);
    float4 v1 = *reinterpret_cast<const float4*>(&yr[256 + tid * 4]);
    float s = v0.x + v0.y + v0.z + v0.w + v1.x + v1.y + v1.z + v1.w;
    float ss = v0.x * v0.x + v0.y * v0.y + v0.z * v0.z + v0.w * v0.w +
               v1.x * v1.x + v1.y * v1.y + v1.z * v1.z + v1.w * v1.w;
#pragma unroll
    for (int off = 32; off; off >>= 1) {
        s  += __shfl_xor(s, off);
        ss += __shfl_xor(ss, off);
    }
    float mean = s * (1.0f / 512.0f);
    float var = ss * (1.0f / 512.0f) - mean * mean;
    float rstd = rsqrtf(var + EPS);

    float* xr = x + (size_t)row * DD;
    float vals[8] = {v0.x, v0.y, v0.z, v0.w, v1.x, v1.y, v1.z, v1.w};
#pragma unroll
    for (int e = 0; e < 8; ++e) {
        int d = (e < 4) ? (tid * 4 + e) : (256 + tid * 4 + (e - 4));
        float nrm = (vals[e] - mean) * rstd * g[d] + bta[d];
        float xo = xr[d] + nrm;
        xr[d] = xo;
        x_bf[(size_t)row * DD + d] = __float2bfloat16(xo);
    }
}

// ---------------- coalesced layer-output transpose: x -> out[b][t][l][d][hw]
__global__ __launch_bounds__(256) void out_transpose(const float* __restrict__ x,
                                                     float* __restrict__ out, int l) {
    __shared__ float tile[64][65];
    const int blk = blockIdx.x;          // 512 = t(16) * b(4) * dc(8)
    const int dc = blk & 7;
    const int b  = (blk >> 3) & 3;
    const int t  = blk >> 5;
    const int tid = threadIdx.x;
#pragma unroll
    for (int it = 0; it < 4; ++it) {
        int c = tid + it * 256;          // 0..1023
        int hw = c >> 4, f4 = c & 15;
        const float* src = x + (size_t)((t * 64 + hw) * 4 + b) * 512 + dc * 64 + f4 * 4;
        float4 v = *reinterpret_cast<const float4*>(src);
        tile[hw][f4 * 4 + 0] = v.x; tile[hw][f4 * 4 + 1] = v.y;
        tile[hw][f4 * 4 + 2] = v.z; tile[hw][f4 * 4 + 3] = v.w;
    }
    __syncthreads();
    size_t ob = (((size_t)(b * 16 + t) * 4 + l) * 512 + dc * 64) * 64;
#pragma unroll
    for (int it = 0; it < 4; ++it) {
        int c = tid + it * 256;
        int d = c >> 4, f4 = c & 15;
        float4 v = make_float4(tile[f4 * 4 + 0][d], tile[f4 * 4 + 1][d],
                               tile[f4 * 4 + 2][d], tile[f4 * 4 + 3][d]);
        *reinterpret_cast<float4*>(out + ob + (size_t)d * 64 + f4 * 4) = v;
    }
}

// ---------------- launcher ----------------
extern "C" void kernel_launch(void* const* d_in, const int* in_sizes, int n_in,
                              void* d_out, int out_size, void* d_ws, size_t ws_size,
                              hipStream_t stream) {
    const float* z    = (const float*)d_in[0];
    const float* Wq   = (const float*)d_in[1];
    const float* Wk   = (const float*)d_in[2];
    const float* Wv   = (const float*)d_in[3];
    const float* Wo   = (const float*)d_in[4];
    const float* W1   = (const float*)d_in[5];
    const float* b1   = (const float*)d_in[6];
    const float* W2   = (const float*)d_in[7];
    const float* b2   = (const float*)d_in[8];
    const float* ln1g = (const float*)d_in[9];
    const float* ln1b = (const float*)d_in[10];
    const float* ln2g = (const float*)d_in[11];
    const float* ln2b = (const float*)d_in[12];
    float* out = (float*)d_out;

    const size_t MB = 1u << 20;
    char* base = (char*)d_ws;
    float*          x     = (float*)(base);                       // 8 MB
    __hip_bfloat16* x_bf  = (__hip_bfloat16*)(base + 8  * MB);    // 4 MB
    __hip_bfloat16* q_bf  = (__hip_bfloat16*)(base + 12 * MB);    // 4 MB
    __hip_bfloat16* k_bf  = (__hip_bfloat16*)(base + 16 * MB);    // 4 MB
    __hip_bfloat16* v_bf  = (__hip_bfloat16*)(base + 20 * MB);    // 4 MB
    __hip_bfloat16* av_bf = (__hip_bfloat16*)(base + 24 * MB);    // 4 MB
    float*          tmp   = (float*)(base + 28 * MB);             // 8 MB
    __hip_bfloat16* wall  = (__hip_bfloat16*)(base + 36 * MB);    // 24 MB (4 layers)
    __hip_bfloat16* ff1_bf = q_bf;               // aliases q..av after attention
    unsigned short* vt    = (unsigned short*)tmp; // vt (4MB) in tmp (dead here)

    const size_t WL = 4 * 512 * 512 + 2 * 512 * 2048;   // per-layer weight elems

    embed_kernel<<<512, 256, 0, stream>>>(z, x, x_bf);
    wt_convert<<<dim3(3072, 4), 256, 0, stream>>>(Wq, Wk, Wv, Wo, W1, W2, wall);

    for (int l = 0; l < 4; ++l) {
        __hip_bfloat16* wl  = wall + (size_t)l * WL;
        __hip_bfloat16* wqt = wl;
        __hip_bfloat16* wkt = wqt + 512 * 512;
        __hip_bfloat16* wvt = wkt + 512 * 512;
        __hip_bfloat16* wot = wvt + 512 * 512;
        __hip_bfloat16* w1t = wot + 512 * 512;     // [2048][512]
        __hip_bfloat16* w2t = w1t + 512 * 2048;    // [512][2048]

        gemm_qkv64<<<dim3(512, 1, 3), 256, 0, stream>>>(x_bf, wqt, wkt, wvt,
                                                        q_bf, k_bf, v_bf);

        transpose_v<<<dim3(16, 32), 256, 0, stream>>>((const unsigned short*)v_bf, vt);

        attn_mfma<<<512, 256, 0, stream>>>(
            (const unsigned short*)q_bf, (const unsigned short*)k_bf,
            vt, (unsigned short*)av_bf);

        gemm64_k<false, false, false><<<512, 256, 0, stream>>>(
            av_bf, wot, nullptr, (void*)tmp, 512);
        add_ln_kernel<<<MROWS, 64, 0, stream>>>(tmp, ln1g + l * 512, ln1b + l * 512,
                                                x, x_bf);

        gemm_k<true, true, true><<<512, 256, 0, stream>>>(
            x_bf, w1t, b1 + l * 2048, (void*)ff1_bf, 2048, 512, 16);
        gemm64_k<true, false, false><<<512, 256, 0, stream>>>(
            ff1_bf, w2t, b2 + l * 512, (void*)tmp, 2048);
        add_ln_kernel<<<MROWS, 64, 0, stream>>>(tmp, ln2g + l * 512, ln2b + l * 512,
                                                x, x_bf);
        out_transpose<<<512, 256, 0, stream>>>(x, out, l);
    }
}

// Round 9
// 439.779 us; speedup vs baseline: 1.4800x; 1.0578x over previous
//
#include <hip/hip_runtime.h>
#include <hip/hip_bf16.h>
#include <math.h>

// Transformer: L=4, D=512, NH=8, DH=64, DFF=2048, Tp=1024, B=4
// x layout: (Tp, B, D) rows: row = i*B + b, M = 4096.

#define TP 1024
#define BB 4
#define DD 512
#define DHEAD 64
#define DFF 2048
#define MROWS (TP*BB)   // 4096
#define EPS 1e-5f
#define CSC 0.18033688011112042f   // 0.125 * log2(e)

typedef __attribute__((ext_vector_type(8))) short bf16x8;
typedef __attribute__((ext_vector_type(4))) float f32x4;

__device__ __forceinline__ float b2f(unsigned short u) {
    union { unsigned int i; float f; } z; z.i = ((unsigned int)u) << 16; return z.f;
}
__device__ __forceinline__ unsigned short f2bu(float f) {
    __hip_bfloat16 h = __float2bfloat16(f);
    return *reinterpret_cast<unsigned short*>(&h);
}

#define WAITV0() asm volatile("s_waitcnt vmcnt(0)" ::: "memory")
#define WAITV4() asm volatile("s_waitcnt vmcnt(4)" ::: "memory")
#define WAITV8() asm volatile("s_waitcnt vmcnt(8)" ::: "memory")
#define WAITL0() asm volatile("s_waitcnt lgkmcnt(0)" ::: "memory")
__device__ __forceinline__ void hard_barrier() {
    __builtin_amdgcn_sched_barrier(0);
    __builtin_amdgcn_s_barrier();
    __builtin_amdgcn_sched_barrier(0);
}
__device__ __forceinline__ void waitv_ahead(int ahead) {
    if (ahead == 2) WAITV8();
    else if (ahead == 1) WAITV4();
    else WAITV0();
}
#define GLOAD(gp, lp) __builtin_amdgcn_global_load_lds( \
    (const __attribute__((address_space(1))) void*)(gp), \
    (__attribute__((address_space(3))) void*)(lp), 16, 0, 0)

// 4-slot swizzle for [rows][32 bf16] tiles (64B rows)
__device__ __forceinline__ int fsw(int row) { return (row ^ (row >> 2)) & 3; }

// ---------------- embed (coalesced via LDS transpose) ----------------------
__global__ __launch_bounds__(256) void embed_kernel(const float* __restrict__ z,
                                                    float* __restrict__ x,
                                                    __hip_bfloat16* __restrict__ x_bf) {
    __shared__ float tile[64][65];
    const int blk = blockIdx.x;
    const int dc = blk & 7, b = (blk >> 3) & 3, t = blk >> 5;
    const int tid = threadIdx.x;
#pragma unroll
    for (int it = 0; it < 4; ++it) {
        int idx = it * 256 + tid;
        int d_i = idx >> 4, hw4 = (idx & 15) * 4;
        int d = dc * 64 + d_i;
        float4 v = *reinterpret_cast<const float4*>(
            z + ((size_t)((b * 16 + t) * 512 + d)) * 64 + hw4);
        int j = d & 255;
        float freq = expf(-(float)(2 * j) * (9.210340371976184f / 512.0f));
        int i0 = t * 64 + hw4;
#pragma unroll
        for (int e = 0; e < 4; ++e) {
            float si = (float)(i0 + e) * freq;
            float pe = (d < 256) ? sinf(si) : cosf(si);
            tile[d_i][hw4 + e] = ((&v.x)[e]) + pe;
        }
    }
    __syncthreads();
#pragma unroll
    for (int it = 0; it < 4; ++it) {
        int idx = it * 256 + tid;
        int hw_o = idx >> 4, dq = (idx & 15) * 4;
        int row = (t * 64 + hw_o) * 4 + b;
        float4 v = make_float4(tile[dq][hw_o], tile[dq + 1][hw_o],
                               tile[dq + 2][hw_o], tile[dq + 3][hw_o]);
        *reinterpret_cast<float4*>(x + (size_t)row * 512 + dc * 64 + dq) = v;
        ushort4 u;
        u.x = f2bu(v.x); u.y = f2bu(v.y); u.z = f2bu(v.z); u.w = f2bu(v.w);
        *reinterpret_cast<ushort4*>((unsigned short*)x_bf + (size_t)row * 512 + dc * 64 + dq) = u;
    }
}

// ---------------- weight transpose+convert, ALL layers in one dispatch -----
__global__ __launch_bounds__(256) void wt_convert(
    const float* __restrict__ Wq, const float* __restrict__ Wk,
    const float* __restrict__ Wv, const float* __restrict__ Wo,
    const float* __restrict__ W1, const float* __restrict__ W2,
    __hip_bfloat16* __restrict__ wall) {
    __shared__ float tile[32][33];
    const int l = blockIdx.y;
    __hip_bfloat16* wl = wall + (size_t)l * (4 * 512 * 512 + 2 * 512 * 2048);
    int b = blockIdx.x;
    const float* src; __hip_bfloat16* dst; int R, C, local, cbs;
    if (b < 1024) {
        int m = b >> 8; local = b & 255; R = 512; C = 512; cbs = 4;
        src = ((m == 0) ? Wq : (m == 1) ? Wk : (m == 2) ? Wv : Wo) + (size_t)l * 512 * 512;
        dst = wl + m * 512 * 512;
    } else if (b < 2048) {
        local = b - 1024; R = 512; C = 2048; cbs = 6;
        src = W1 + (size_t)l * 512 * 2048; dst = wl + 4 * 512 * 512;
    } else {
        local = b - 2048; R = 2048; C = 512; cbs = 4;
        src = W2 + (size_t)l * 2048 * 512; dst = wl + 4 * 512 * 512 + 512 * 2048;
    }
    int bx = local & ((1 << cbs) - 1), by = local >> cbs;
    int tx = threadIdx.x & 31, ty = threadIdx.x >> 5;
#pragma unroll
    for (int j = 0; j < 4; ++j)
        tile[ty + j * 8][tx] = src[(size_t)(by * 32 + ty + j * 8) * C + bx * 32 + tx];
    __syncthreads();
#pragma unroll
    for (int j = 0; j < 4; ++j)
        dst[(size_t)(bx * 32 + ty + j * 8) * R + by * 32 + tx] =
            __float2bfloat16(tile[tx][ty + j * 8]);
}

// ---------------- bf16 MFMA GEMM 128x128 (FF1): BK=32, ring-4 counted ------
template<bool BIAS, bool RELU, bool OUT_BF16>
__global__ __launch_bounds__(256) void gemm_k(const __hip_bfloat16* __restrict__ A,
                                              const __hip_bfloat16* __restrict__ Bt,
                                              const float* __restrict__ bias,
                                              void* __restrict__ Cout,
                                              int N, int K, int ntx) {
    __shared__ __hip_bfloat16 As[4][128 * 32];
    __shared__ __hip_bfloat16 Bs[4][128 * 32];

    const int lb = blockIdx.x;
    const int wg = (lb & 7) * (gridDim.x >> 3) + (lb >> 3);
    const int m0 = (wg / ntx) * 128;
    const int n0 = (wg % ntx) * 128;

    const int tid  = threadIdx.x;
    const int wave = tid >> 6;
    const int lane = tid & 63;
    const int lr   = lane & 15;
    const int hi   = lane >> 4;
    const int lk   = (hi ^ fsw(lr)) << 3;     // swizzled k-slot
    const int wr   = (wave >> 1) * 64;
    const int wc   = (wave & 1) * 64;

    f32x4 acc[4][4];
#pragma unroll
    for (int i = 0; i < 4; ++i)
#pragma unroll
        for (int j = 0; j < 4; ++j) acc[i][j] = (f32x4){0.f, 0.f, 0.f, 0.f};

    const int c0 = tid, c1 = tid + 256;
    const __hip_bfloat16* a0 = A  + (size_t)(m0 + (c0 >> 2)) * K + (((c0 & 3) ^ fsw(c0 >> 2)) << 3);
    const __hip_bfloat16* a1 = A  + (size_t)(m0 + (c1 >> 2)) * K + (((c1 & 3) ^ fsw(c1 >> 2)) << 3);
    const __hip_bfloat16* b0 = Bt + (size_t)(n0 + (c0 >> 2)) * K + (((c0 & 3) ^ fsw(c0 >> 2)) << 3);
    const __hip_bfloat16* b1 = Bt + (size_t)(n0 + (c1 >> 2)) * K + (((c1 & 3) ^ fsw(c1 >> 2)) << 3);
    const int o0 = wave * 512, o1 = 2048 + wave * 512;

    const int nst = K >> 5;
#pragma unroll
    for (int s = 0; s < 3; ++s) {
        GLOAD(a0 + s * 32, &As[s][o0]); GLOAD(a1 + s * 32, &As[s][o1]);
        GLOAD(b0 + s * 32, &Bs[s][o0]); GLOAD(b1 + s * 32, &Bs[s][o1]);
    }

    for (int k = 0; k < nst; ++k) {
        const int ahead = (nst - 1 - k >= 2) ? 2 : (nst - 1 - k);
        waitv_ahead(ahead);
        hard_barrier();                       // stage(k) ready; buf (k+3)&3 free
        if (k + 3 < nst) {
            const int kk = (k + 3) << 5, bb = (k + 3) & 3;
            GLOAD(a0 + kk, &As[bb][o0]); GLOAD(a1 + kk, &As[bb][o1]);
            GLOAD(b0 + kk, &Bs[bb][o0]); GLOAD(b1 + kk, &Bs[bb][o1]);
        }
        const int buf = k & 3;
        bf16x8 af[4], bfv[4];
#pragma unroll
        for (int i = 0; i < 4; ++i)
            af[i] = *reinterpret_cast<const bf16x8*>(&As[buf][(size_t)(wr + i * 16 + lr) * 32 + lk]);
#pragma unroll
        for (int j = 0; j < 4; ++j)
            bfv[j] = *reinterpret_cast<const bf16x8*>(&Bs[buf][(size_t)(wc + j * 16 + lr) * 32 + lk]);
        __builtin_amdgcn_s_setprio(1);
#pragma unroll
        for (int i = 0; i < 4; ++i)
#pragma unroll
            for (int j = 0; j < 4; ++j)
                acc[i][j] = __builtin_amdgcn_mfma_f32_16x16x32_bf16(af[i], bfv[j], acc[i][j], 0, 0, 0);
        __builtin_amdgcn_s_setprio(0);
    }

#pragma unroll
    for (int j = 0; j < 4; ++j) {
        int col = n0 + wc + j * 16 + lr;
        float bv = BIAS ? bias[col] : 0.0f;
#pragma unroll
        for (int i = 0; i < 4; ++i) {
            int row = m0 + wr + i * 16 + (hi << 2);
#pragma unroll
            for (int r = 0; r < 4; ++r) {
                float v = acc[i][j][r] + bv;
                if (RELU) v = fmaxf(v, 0.0f);
                if (OUT_BF16)
                    ((unsigned short*)Cout)[(size_t)(row + r) * N + col] = f2bu(v);
                else
                    ((float*)Cout)[(size_t)(row + r) * N + col] = v;
            }
        }
    }
}

// ---------------- bf16 MFMA GEMM 64x64, BK=64, ring-4 counted vmcnt --------
// LDS tile: [64 rows][64 K] bf16 = 8 slots of 16B/row; slot ^= row&7.
template<bool BIAS, bool RELU, bool OUT_BF16>
__device__ __forceinline__ void gemm64_body(const __hip_bfloat16* __restrict__ A,
                                            const __hip_bfloat16* __restrict__ Bt,
                                            const float* __restrict__ bias,
                                            void* __restrict__ Cout, int K,
                                            float scale,
                                            __hip_bfloat16* As, __hip_bfloat16* Bs) {
    const int lb = blockIdx.x;
    const int wg = (lb & 7) * (gridDim.x >> 3) + (lb >> 3);
    const int m0 = (wg >> 3) * 64;
    const int n0 = (wg & 7) * 64;

    const int tid  = threadIdx.x;
    const int wave = tid >> 6;
    const int lane = tid & 63;
    const int lr   = lane & 15;
    const int hi   = lane >> 4;
    const int wr   = (wave >> 1) * 32;
    const int wc   = (wave & 1) * 32;

    f32x4 acc[2][2];
#pragma unroll
    for (int i = 0; i < 2; ++i)
#pragma unroll
        for (int j = 0; j < 2; ++j) acc[i][j] = (f32x4){0.f, 0.f, 0.f, 0.f};

    // staging: tile = 512 chunks of 16B; thread covers chunks tid, tid+256.
    const int c0 = tid, c1 = tid + 256;
    const __hip_bfloat16* a0 = A  + (size_t)(m0 + (c0 >> 3)) * K + (((c0 & 7) ^ ((c0 >> 3) & 7)) << 3);
    const __hip_bfloat16* a1 = A  + (size_t)(m0 + (c1 >> 3)) * K + (((c1 & 7) ^ ((c1 >> 3) & 7)) << 3);
    const __hip_bfloat16* b0 = Bt + (size_t)(n0 + (c0 >> 3)) * K + (((c0 & 7) ^ ((c0 >> 3) & 7)) << 3);
    const __hip_bfloat16* b1 = Bt + (size_t)(n0 + (c1 >> 3)) * K + (((c1 & 7) ^ ((c1 >> 3) & 7)) << 3);
    const int o0 = wave * 512, o1 = 2048 + wave * 512;   // element offsets

    const int nst = K >> 6;
#pragma unroll
    for (int s = 0; s < 3; ++s) {
        if (s < 3 && s < nst) {
            GLOAD(a0 + s * 64, As + s * 4096 + o0); GLOAD(a1 + s * 64, As + s * 4096 + o1);
            GLOAD(b0 + s * 64, Bs + s * 4096 + o0); GLOAD(b1 + s * 64, Bs + s * 4096 + o1);
        }
    }

    for (int k = 0; k < nst; ++k) {
        const int ahead = (nst - 1 - k >= 2) ? 2 : (nst - 1 - k);
        waitv_ahead(ahead);
        hard_barrier();
        if (k + 3 < nst) {
            const int kk = (k + 3) << 6;
            const int bo = ((k + 3) & 3) * 4096;
            GLOAD(a0 + kk, As + bo + o0); GLOAD(a1 + kk, As + bo + o1);
            GLOAD(b0 + kk, Bs + bo + o0); GLOAD(b1 + kk, Bs + bo + o1);
        }
        const __hip_bfloat16* Ab = As + (k & 3) * 4096;
        const __hip_bfloat16* Bb = Bs + (k & 3) * 4096;
        __builtin_amdgcn_s_setprio(1);
#pragma unroll
        for (int ks = 0; ks < 2; ++ks) {
            bf16x8 af[2], bfv[2];
#pragma unroll
            for (int i = 0; i < 2; ++i) {
                int row = wr + i * 16 + lr;
                af[i] = *reinterpret_cast<const bf16x8*>(
                    &Ab[(size_t)row * 64 + (((ks * 4 + hi) ^ (row & 7)) << 3)]);
            }
#pragma unroll
            for (int j = 0; j < 2; ++j) {
                int row = wc + j * 16 + lr;
                bfv[j] = *reinterpret_cast<const bf16x8*>(
                    &Bb[(size_t)row * 64 + (((ks * 4 + hi) ^ (row & 7)) << 3)]);
            }
#pragma unroll
            for (int i = 0; i < 2; ++i)
#pragma unroll
                for (int j = 0; j < 2; ++j)
                    acc[i][j] = __builtin_amdgcn_mfma_f32_16x16x32_bf16(af[i], bfv[j], acc[i][j], 0, 0, 0);
        }
        __builtin_amdgcn_s_setprio(0);
    }

#pragma unroll
    for (int j = 0; j < 2; ++j) {
        int col = n0 + wc + j * 16 + lr;
        float bv = BIAS ? bias[col] : 0.0f;
#pragma unroll
        for (int i = 0; i < 2; ++i) {
            int row = m0 + wr + i * 16 + (hi << 2);
#pragma unroll
            for (int r = 0; r < 4; ++r) {
                float v = acc[i][j][r] * scale + bv;
                if (RELU) v = fmaxf(v, 0.0f);
                if (OUT_BF16)
                    ((unsigned short*)Cout)[(size_t)(row + r) * 512 + col] = f2bu(v);
                else
                    ((float*)Cout)[(size_t)(row + r) * 512 + col] = v;
            }
        }
    }
}

template<bool BIAS, bool RELU, bool OUT_BF16>
__global__ __launch_bounds__(256) void gemm64_k(const __hip_bfloat16* __restrict__ A,
                                                const __hip_bfloat16* __restrict__ Bt,
                                                const float* __restrict__ bias,
                                                void* __restrict__ Cout, int K) {
    __shared__ __hip_bfloat16 As[4 * 64 * 64];
    __shared__ __hip_bfloat16 Bs[4 * 64 * 64];
    gemm64_body<BIAS, RELU, OUT_BF16>(A, Bt, bias, Cout, K, 1.0f, As, Bs);
}

__global__ __launch_bounds__(256) void gemm_qkv64(const __hip_bfloat16* __restrict__ A,
                                                  const __hip_bfloat16* __restrict__ B0,
                                                  const __hip_bfloat16* __restrict__ B1,
                                                  const __hip_bfloat16* __restrict__ B2,
                                                  __hip_bfloat16* __restrict__ C0,
                                                  __hip_bfloat16* __restrict__ C1,
                                                  __hip_bfloat16* __restrict__ C2) {
    __shared__ __hip_bfloat16 As[4 * 64 * 64];
    __shared__ __hip_bfloat16 Bs[4 * 64 * 64];
    int sel = blockIdx.z;
    const __hip_bfloat16* Bt = (sel == 0) ? B0 : (sel == 1) ? B1 : B2;
    __hip_bfloat16* C = (sel == 0) ? C0 : (sel == 1) ? C1 : C2;
    float scale = (sel == 0) ? CSC : 1.0f;   // fold 0.125*log2(e) into Q
    gemm64_body<false, false, true>(A, Bt, nullptr, (void*)C, 512, scale, As, Bs);
}

// ---------------- V transpose: v (tok,b,n,d) -> vt[bn][d][1024 keys] --------
__global__ __launch_bounds__(256) void transpose_v(const unsigned short* __restrict__ v,
                                                   unsigned short* __restrict__ vt) {
    __shared__ unsigned short t[64][72];
    const int kb = blockIdx.x;
    const int bn = blockIdx.y;
    const int b = bn >> 3, n = bn & 7;
    const int tid = threadIdx.x;
#pragma unroll
    for (int it = 0; it < 2; ++it) {
        int c = tid + it * 256;
        int row = c >> 3, d0 = (c & 7) * 8;
        const unsigned short* src =
            v + ((size_t)((kb * 64 + row) * 4 + b)) * 512 + n * 64 + d0;
        bf16x8 xv = *reinterpret_cast<const bf16x8*>(src);
#pragma unroll
        for (int e = 0; e < 8; ++e) t[row][d0 + e] = (unsigned short)xv[e];
    }
    __syncthreads();
#pragma unroll
    for (int it = 0; it < 2; ++it) {
        int c = tid + it * 256;
        int d = c >> 3, k0 = (c & 7) * 8;
        bf16x8 o;
#pragma unroll
        for (int e = 0; e < 8; ++e) o[e] = (short)t[k0 + e][d];
        *reinterpret_cast<bf16x8*>(vt + ((size_t)(bn * 64 + d)) * 1024 + kb * 64 + k0) = o;
    }
}

// ---------------- MFMA block-causal flash attention (flat softmax) ---------
__device__ __forceinline__ int aswz(int row, int col) {
    return (row * 64 + col) ^ ((row & 7) << 3);
}

__device__ __forceinline__ void stage_tile(const unsigned short* gbase, int stride,
                                           unsigned short* lds, int wave, int tid) {
#pragma unroll
    for (int it = 0; it < 2; ++it) {
        int c = tid + it * 256;
        int row = c >> 3;
        int i = (c & 7) ^ (row & 7);
        const unsigned short* g = gbase + (size_t)row * stride + i * 8;
        __builtin_amdgcn_global_load_lds(
            (const __attribute__((address_space(1))) void*)g,
            (__attribute__((address_space(3))) void*)(lds + it * 2048 + wave * 512),
            16, 0, 0);
    }
}

__global__ __launch_bounds__(256) void attn_mfma(const unsigned short* __restrict__ q,
                                                 const unsigned short* __restrict__ k,
                                                 const unsigned short* __restrict__ vt,
                                                 unsigned short* __restrict__ av) {
    __shared__ unsigned short Qs[64 * 64];
    __shared__ unsigned short Ks[4][64 * 64];
    __shared__ unsigned short Vts[4][64 * 64];
    __shared__ unsigned short Ps[64 * 64];

    const int tid = threadIdx.x;
    const int wave = tid >> 6, lane = tid & 63;
    const int lr = lane & 15, hi = lane >> 4;
    const int wr = wave * 16;

    const int p = blockIdx.x;            // XCD-affinity swizzle
    const int xcd = p & 7, idx = p >> 3;
    const int bn = xcd * 4 + (idx & 3);
    const int qb = 15 - (idx >> 2);      // long blocks first within XCD
    const int b = bn >> 3, n = bn & 7;

    const unsigned short* kcol  = k  + (size_t)b * 512 + n * 64;
    const unsigned short* vtrow = vt + (size_t)(bn * 64) * 1024;

    stage_tile(q + ((size_t)(qb * 64) * 4 + b) * 512 + n * 64, 2048, Qs, wave, tid);
    stage_tile(kcol, 2048, Ks[0], wave, tid);
    stage_tile(vtrow, 1024, Vts[0], wave, tid);
    if (qb >= 1) {
        stage_tile(kcol + (size_t)64 * 2048, 2048, Ks[1], wave, tid);
        stage_tile(vtrow + 64, 1024, Vts[1], wave, tid);
    }
    if (qb >= 2) {
        stage_tile(kcol + (size_t)128 * 2048, 2048, Ks[2], wave, tid);
        stage_tile(vtrow + 128, 1024, Vts[2], wave, tid);
    }

    f32x4 o_acc[4], l_acc;
#pragma unroll
    for (int db = 0; db < 4; ++db) o_acc[db] = (f32x4){0.f, 0.f, 0.f, 0.f};
    l_acc = (f32x4){0.f, 0.f, 0.f, 0.f};

    bf16x8 onesf;
#pragma unroll
    for (int e = 0; e < 8; ++e) onesf[e] = (short)0x3F80;   // bf16 1.0

    bf16x8 qf[2];

    for (int kb = 0; kb <= qb; ++kb) {
        const int ahead = (qb - kb >= 2) ? 2 : (qb - kb);
        waitv_ahead(ahead);
        hard_barrier();                  // stage(kb) fully in LDS for all waves
        if (kb + 3 <= qb) {
            stage_tile(kcol + (size_t)(kb + 3) * 64 * 2048, 2048,
                       Ks[(kb + 3) & 3], wave, tid);
            stage_tile(vtrow + (kb + 3) * 64, 1024, Vts[(kb + 3) & 3], wave, tid);
        }
        if (kb == 0) {
#pragma unroll
            for (int ks = 0; ks < 2; ++ks)
                qf[ks] = *reinterpret_cast<const bf16x8*>(
                    (const unsigned short*)Qs + aswz(wr + lr, ks * 32 + hi * 8));
        }
        const unsigned short* Kb = Ks[kb & 3];
        const unsigned short* Vb = Vts[kb & 3];

        f32x4 sf[4];
#pragma unroll
        for (int jb = 0; jb < 4; ++jb) sf[jb] = (f32x4){0.f, 0.f, 0.f, 0.f};
        __builtin_amdgcn_s_setprio(1);
#pragma unroll
        for (int ks = 0; ks < 2; ++ks) {
            bf16x8 a = qf[ks];
#pragma unroll
            for (int jb = 0; jb < 4; ++jb) {
                bf16x8 kf = *reinterpret_cast<const bf16x8*>(
                    Kb + aswz(jb * 16 + lr, ks * 32 + hi * 8));
                sf[jb] = __builtin_amdgcn_mfma_f32_16x16x32_bf16(a, kf, sf[jb], 0, 0, 0);
            }
        }
        __builtin_amdgcn_s_setprio(0);

        // flat softmax: p = exp2(min(s,100)); Q pre-scaled by 0.125*log2(e)
#pragma unroll
        for (int jb = 0; jb < 4; ++jb)
#pragma unroll
            for (int r = 0; r < 4; ++r) {
                float pe = exp2f(fminf(sf[jb][r], 100.0f));
                Ps[aswz(wr + 4 * hi + r, jb * 16 + lr)] = f2bu(pe);
            }
        WAITL0();
        hard_barrier();                  // P visible; vmcnt prefetch in flight

        __builtin_amdgcn_s_setprio(1);
#pragma unroll
        for (int ks = 0; ks < 2; ++ks) {
            bf16x8 pf = *reinterpret_cast<const bf16x8*>(
                (const unsigned short*)Ps + aswz(wr + lr, ks * 32 + hi * 8));
            l_acc = __builtin_amdgcn_mfma_f32_16x16x32_bf16(pf, onesf, l_acc, 0, 0, 0);
#pragma unroll
            for (int db = 0; db < 4; ++db) {
                bf16x8 vf = *reinterpret_cast<const bf16x8*>(
                    Vb + aswz(db * 16 + lr, ks * 32 + hi * 8));
                o_acc[db] = __builtin_amdgcn_mfma_f32_16x16x32_bf16(pf, vf, o_acc[db], 0, 0, 0);
            }
        }
        __builtin_amdgcn_s_setprio(0);
    }

#pragma unroll
    for (int r = 0; r < 4; ++r) {
        float inv = 1.0f / l_acc[r];
        int row = qb * 64 + wr + 4 * hi + r;
#pragma unroll
        for (int db = 0; db < 4; ++db)
            av[((size_t)row * 4 + b) * 512 + n * 64 + db * 16 + lr] =
                f2bu(o_acc[db][r] * inv);
    }
}

// ---------------- LN(y)*g+b + x -> x (f32 + bf16) ------
__global__ __launch_bounds__(64) void add_ln_kernel(const float* __restrict__ y,
                                                    const float* __restrict__ g,
                                                    const float* __restrict__ bta,
                                                    float* __restrict__ x,
                                                    __hip_bfloat16* __restrict__ x_bf) {
    const int row = blockIdx.x;     // 0..4095
    const int tid = threadIdx.x;    // 0..63
    const float* yr = y + (size_t)row * DD;
    float4 v0 = *reinterpret_cast<const float4*>(&yr[tid * 4]);
    float4 v1 = *reinterpret_cast<const float4*>(&yr[256 + tid * 4]);
    float s = v0.x + v0.y + v0.z + v0.w + v1.x + v1.y + v1.z + v1.w;
    float ss = v0.x * v0.x + v0.y * v0.y + v0.z * v0.z + v0.w * v0.w +
               v1.x * v1.x + v1.y * v1.y + v1.z * v1.z + v1.w * v1.w;
#pragma unroll
    for (int off = 32; off; off >>= 1) {
        s  += __shfl_xor(s, off);
        ss += __shfl_xor(ss, off);
    }
    float mean = s * (1.0f / 512.0f);
    float var = ss * (1.0f / 512.0f) - mean * mean;
    float rstd = rsqrtf(var + EPS);

    float* xr = x + (size_t)row * DD;
    float vals[8] = {v0.x, v0.y, v0.z, v0.w, v1.x, v1.y, v1.z, v1.w};
#pragma unroll
    for (int e = 0; e < 8; ++e) {
        int d = (e < 4) ? (tid * 4 + e) : (256 + tid * 4 + (e - 4));
        float nrm = (vals[e] - mean) * rstd * g[d] + bta[d];
        float xo = xr[d] + nrm;
        xr[d] = xo;
        x_bf[(size_t)row * DD + d] = __float2bfloat16(xo);
    }
}

// ---------------- coalesced layer-output transpose: x -> out[b][t][l][d][hw]
__global__ __launch_bounds__(256) void out_transpose(const float* __restrict__ x,
                                                     float* __restrict__ out, int l) {
    __shared__ float tile[64][65];
    const int blk = blockIdx.x;          // 512 = t(16) * b(4) * dc(8)
    const int dc = blk & 7;
    const int b  = (blk >> 3) & 3;
    const int t  = blk >> 5;
    const int tid = threadIdx.x;
#pragma unroll
    for (int it = 0; it < 4; ++it) {
        int c = tid + it * 256;          // 0..1023
        int hw = c >> 4, f4 = c & 15;
        const float* src = x + (size_t)((t * 64 + hw) * 4 + b) * 512 + dc * 64 + f4 * 4;
        float4 v = *reinterpret_cast<const float4*>(src);
        tile[hw][f4 * 4 + 0] = v.x; tile[hw][f4 * 4 + 1] = v.y;
        tile[hw][f4 * 4 + 2] = v.z; tile[hw][f4 * 4 + 3] = v.w;
    }
    __syncthreads();
    size_t ob = (((size_t)(b * 16 + t) * 4 + l) * 512 + dc * 64) * 64;
#pragma unroll
    for (int it = 0; it < 4; ++it) {
        int c = tid + it * 256;
        int d = c >> 4, f4 = c & 15;
        float4 v = make_float4(tile[f4 * 4 + 0][d], tile[f4 * 4 + 1][d],
                               tile[f4 * 4 + 2][d], tile[f4 * 4 + 3][d]);
        *reinterpret_cast<float4*>(out + ob + (size_t)d * 64 + f4 * 4) = v;
    }
}

// ---------------- launcher ----------------
extern "C" void kernel_launch(void* const* d_in, const int* in_sizes, int n_in,
                              void* d_out, int out_size, void* d_ws, size_t ws_size,
                              hipStream_t stream) {
    const float* z    = (const float*)d_in[0];
    const float* Wq   = (const float*)d_in[1];
    const float* Wk   = (const float*)d_in[2];
    const float* Wv   = (const float*)d_in[3];
    const float* Wo   = (const float*)d_in[4];
    const float* W1   = (const float*)d_in[5];
    const float* b1   = (const float*)d_in[6];
    const float* W2   = (const float*)d_in[7];
    const float* b2   = (const float*)d_in[8];
    const float* ln1g = (const float*)d_in[9];
    const float* ln1b = (const float*)d_in[10];
    const float* ln2g = (const float*)d_in[11];
    const float* ln2b = (const float*)d_in[12];
    float* out = (float*)d_out;

    const size_t MB = 1u << 20;
    char* base = (char*)d_ws;
    float*          x     = (float*)(base);                       // 8 MB
    __hip_bfloat16* x_bf  = (__hip_bfloat16*)(base + 8  * MB);    // 4 MB
    __hip_bfloat16* q_bf  = (__hip_bfloat16*)(base + 12 * MB);    // 4 MB
    __hip_bfloat16* k_bf  = (__hip_bfloat16*)(base + 16 * MB);    // 4 MB
    __hip_bfloat16* v_bf  = (__hip_bfloat16*)(base + 20 * MB);    // 4 MB
    __hip_bfloat16* av_bf = (__hip_bfloat16*)(base + 24 * MB);    // 4 MB
    float*          tmp   = (float*)(base + 28 * MB);             // 8 MB
    __hip_bfloat16* wall  = (__hip_bfloat16*)(base + 36 * MB);    // 24 MB (4 layers)
    __hip_bfloat16* ff1_bf = q_bf;               // aliases q..av after attention
    unsigned short* vt    = (unsigned short*)tmp; // vt (4MB) in tmp (dead here)

    const size_t WL = 4 * 512 * 512 + 2 * 512 * 2048;   // per-layer weight elems

    embed_kernel<<<512, 256, 0, stream>>>(z, x, x_bf);
    wt_convert<<<dim3(3072, 4), 256, 0, stream>>>(Wq, Wk, Wv, Wo, W1, W2, wall);

    for (int l = 0; l < 4; ++l) {
        __hip_bfloat16* wl  = wall + (size_t)l * WL;
        __hip_bfloat16* wqt = wl;
        __hip_bfloat16* wkt = wqt + 512 * 512;
        __hip_bfloat16* wvt = wkt + 512 * 512;
        __hip_bfloat16* wot = wvt + 512 * 512;
        __hip_bfloat16* w1t = wot + 512 * 512;     // [2048][512]
        __hip_bfloat16* w2t = w1t + 512 * 2048;    // [512][2048]

        gemm_qkv64<<<dim3(512, 1, 3), 256, 0, stream>>>(x_bf, wqt, wkt, wvt,
                                                        q_bf, k_bf, v_bf);

        transpose_v<<<dim3(16, 32), 256, 0, stream>>>((const unsigned short*)v_bf, vt);

        attn_mfma<<<512, 256, 0, stream>>>(
            (const unsigned short*)q_bf, (const unsigned short*)k_bf,
            vt, (unsigned short*)av_bf);

        gemm64_k<false, false, false><<<512, 256, 0, stream>>>(
            av_bf, wot, nullptr, (void*)tmp, 512);
        add_ln_kernel<<<MROWS, 64, 0, stream>>>(tmp, ln1g + l * 512, ln1b + l * 512,
                                                x, x_bf);

        gemm_k<true, true, true><<<512, 256, 0, stream>>>(
            x_bf, w1t, b1 + l * 2048, (void*)ff1_bf, 2048, 512, 16);
        gemm64_k<true, false, false><<<512, 256, 0, stream>>>(
            ff1_bf, w2t, b2 + l * 512, (void*)tmp, 2048);
        add_ln_kernel<<<MROWS, 64, 0, stream>>>(tmp, ln2g + l * 512, ln2b + l * 512,
                                                x, x_bf);
        out_transpose<<<512, 256, 0, stream>>>(x, out, l);
    }
}

// Round 10
// 418.950 us; speedup vs baseline: 1.5536x; 1.0497x over previous
//
#include <hip/hip_runtime.h>
#include <hip/hip_bf16.h>
#include <math.h>

// Transformer: L=4, D=512, NH=8, DH=64, DFF=2048, Tp=1024, B=4
// x layout: (Tp, B, D) rows: row = i*B + b, M = 4096.

#define TP 1024
#define BB 4
#define DD 512
#define DHEAD 64
#define DFF 2048
#define MROWS (TP*BB)   // 4096
#define EPS 1e-5f
#define CSC 0.18033688011112042f   // 0.125 * log2(e)

typedef __attribute__((ext_vector_type(8))) short bf16x8;
typedef __attribute__((ext_vector_type(4))) float f32x4;

__device__ __forceinline__ float b2f(unsigned short u) {
    union { unsigned int i; float f; } z; z.i = ((unsigned int)u) << 16; return z.f;
}
__device__ __forceinline__ unsigned short f2bu(float f) {
    __hip_bfloat16 h = __float2bfloat16(f);
    return *reinterpret_cast<unsigned short*>(&h);
}

#define WAITV0() asm volatile("s_waitcnt vmcnt(0)" ::: "memory")
#define WAITV4() asm volatile("s_waitcnt vmcnt(4)" ::: "memory")
#define WAITV8() asm volatile("s_waitcnt vmcnt(8)" ::: "memory")
#define WAITL0() asm volatile("s_waitcnt lgkmcnt(0)" ::: "memory")
__device__ __forceinline__ void hard_barrier() {
    __builtin_amdgcn_sched_barrier(0);
    __builtin_amdgcn_s_barrier();
    __builtin_amdgcn_sched_barrier(0);
}
__device__ __forceinline__ void waitv_ahead(int ahead) {
    if (ahead == 2) WAITV8();
    else if (ahead == 1) WAITV4();
    else WAITV0();
}
#define GLOAD(gp, lp) __builtin_amdgcn_global_load_lds( \
    (const __attribute__((address_space(1))) void*)(gp), \
    (__attribute__((address_space(3))) void*)(lp), 16, 0, 0)

// 4-slot swizzle for [rows][32 bf16] tiles (64B rows)
__device__ __forceinline__ int fsw(int row) { return (row ^ (row >> 2)) & 3; }

// ---------------- embed (coalesced via LDS transpose) ----------------------
__global__ __launch_bounds__(256) void embed_kernel(const float* __restrict__ z,
                                                    float* __restrict__ x,
                                                    __hip_bfloat16* __restrict__ x_bf) {
    __shared__ float tile[64][65];
    const int blk = blockIdx.x;
    const int dc = blk & 7, b = (blk >> 3) & 3, t = blk >> 5;
    const int tid = threadIdx.x;
#pragma unroll
    for (int it = 0; it < 4; ++it) {
        int idx = it * 256 + tid;
        int d_i = idx >> 4, hw4 = (idx & 15) * 4;
        int d = dc * 64 + d_i;
        float4 v = *reinterpret_cast<const float4*>(
            z + ((size_t)((b * 16 + t) * 512 + d)) * 64 + hw4);
        int j = d & 255;
        float freq = expf(-(float)(2 * j) * (9.210340371976184f / 512.0f));
        int i0 = t * 64 + hw4;
#pragma unroll
        for (int e = 0; e < 4; ++e) {
            float si = (float)(i0 + e) * freq;
            float pe = (d < 256) ? sinf(si) : cosf(si);
            tile[d_i][hw4 + e] = ((&v.x)[e]) + pe;
        }
    }
    __syncthreads();
#pragma unroll
    for (int it = 0; it < 4; ++it) {
        int idx = it * 256 + tid;
        int hw_o = idx >> 4, dq = (idx & 15) * 4;
        int row = (t * 64 + hw_o) * 4 + b;
        float4 v = make_float4(tile[dq][hw_o], tile[dq + 1][hw_o],
                               tile[dq + 2][hw_o], tile[dq + 3][hw_o]);
        *reinterpret_cast<float4*>(x + (size_t)row * 512 + dc * 64 + dq) = v;
        ushort4 u;
        u.x = f2bu(v.x); u.y = f2bu(v.y); u.z = f2bu(v.z); u.w = f2bu(v.w);
        *reinterpret_cast<ushort4*>((unsigned short*)x_bf + (size_t)row * 512 + dc * 64 + dq) = u;
    }
}

// ---------------- weight transpose+convert, ALL layers in one dispatch -----
__global__ __launch_bounds__(256) void wt_convert(
    const float* __restrict__ Wq, const float* __restrict__ Wk,
    const float* __restrict__ Wv, const float* __restrict__ Wo,
    const float* __restrict__ W1, const float* __restrict__ W2,
    __hip_bfloat16* __restrict__ wall) {
    __shared__ float tile[32][33];
    const int l = blockIdx.y;
    __hip_bfloat16* wl = wall + (size_t)l * (4 * 512 * 512 + 2 * 512 * 2048);
    int b = blockIdx.x;
    const float* src; __hip_bfloat16* dst; int R, C, local, cbs;
    if (b < 1024) {
        int m = b >> 8; local = b & 255; R = 512; C = 512; cbs = 4;
        src = ((m == 0) ? Wq : (m == 1) ? Wk : (m == 2) ? Wv : Wo) + (size_t)l * 512 * 512;
        dst = wl + m * 512 * 512;
    } else if (b < 2048) {
        local = b - 1024; R = 512; C = 2048; cbs = 6;
        src = W1 + (size_t)l * 512 * 2048; dst = wl + 4 * 512 * 512;
    } else {
        local = b - 2048; R = 2048; C = 512; cbs = 4;
        src = W2 + (size_t)l * 2048 * 512; dst = wl + 4 * 512 * 512 + 512 * 2048;
    }
    int bx = local & ((1 << cbs) - 1), by = local >> cbs;
    int tx = threadIdx.x & 31, ty = threadIdx.x >> 5;
#pragma unroll
    for (int j = 0; j < 4; ++j)
        tile[ty + j * 8][tx] = src[(size_t)(by * 32 + ty + j * 8) * C + bx * 32 + tx];
    __syncthreads();
#pragma unroll
    for (int j = 0; j < 4; ++j)
        dst[(size_t)(bx * 32 + ty + j * 8) * R + by * 32 + tx] =
            __float2bfloat16(tile[tx][ty + j * 8]);
}

// ---------------- bf16 MFMA GEMM 128x128 (FF1): BK=32, ring-4 counted ------
template<bool BIAS, bool RELU, bool OUT_BF16>
__global__ __launch_bounds__(256) void gemm_k(const __hip_bfloat16* __restrict__ A,
                                              const __hip_bfloat16* __restrict__ Bt,
                                              const float* __restrict__ bias,
                                              void* __restrict__ Cout,
                                              int N, int K, int ntx) {
    __shared__ __hip_bfloat16 As[4][128 * 32];
    __shared__ __hip_bfloat16 Bs[4][128 * 32];

    const int lb = blockIdx.x;
    const int wg = (lb & 7) * (gridDim.x >> 3) + (lb >> 3);
    const int m0 = (wg / ntx) * 128;
    const int n0 = (wg % ntx) * 128;

    const int tid  = threadIdx.x;
    const int wave = tid >> 6;
    const int lane = tid & 63;
    const int lr   = lane & 15;
    const int hi   = lane >> 4;
    const int lk   = (hi ^ fsw(lr)) << 3;     // swizzled k-slot
    const int wr   = (wave >> 1) * 64;
    const int wc   = (wave & 1) * 64;

    f32x4 acc[4][4];
#pragma unroll
    for (int i = 0; i < 4; ++i)
#pragma unroll
        for (int j = 0; j < 4; ++j) acc[i][j] = (f32x4){0.f, 0.f, 0.f, 0.f};

    const int c0 = tid, c1 = tid + 256;
    const __hip_bfloat16* a0 = A  + (size_t)(m0 + (c0 >> 2)) * K + (((c0 & 3) ^ fsw(c0 >> 2)) << 3);
    const __hip_bfloat16* a1 = A  + (size_t)(m0 + (c1 >> 2)) * K + (((c1 & 3) ^ fsw(c1 >> 2)) << 3);
    const __hip_bfloat16* b0 = Bt + (size_t)(n0 + (c0 >> 2)) * K + (((c0 & 3) ^ fsw(c0 >> 2)) << 3);
    const __hip_bfloat16* b1 = Bt + (size_t)(n0 + (c1 >> 2)) * K + (((c1 & 3) ^ fsw(c1 >> 2)) << 3);
    const int o0 = wave * 512, o1 = 2048 + wave * 512;

    const int nst = K >> 5;
#pragma unroll
    for (int s = 0; s < 3; ++s) {
        GLOAD(a0 + s * 32, &As[s][o0]); GLOAD(a1 + s * 32, &As[s][o1]);
        GLOAD(b0 + s * 32, &Bs[s][o0]); GLOAD(b1 + s * 32, &Bs[s][o1]);
    }

    for (int k = 0; k < nst; ++k) {
        const int ahead = (nst - 1 - k >= 2) ? 2 : (nst - 1 - k);
        waitv_ahead(ahead);
        hard_barrier();                       // stage(k) ready; buf (k+3)&3 free
        if (k + 3 < nst) {
            const int kk = (k + 3) << 5, bb = (k + 3) & 3;
            GLOAD(a0 + kk, &As[bb][o0]); GLOAD(a1 + kk, &As[bb][o1]);
            GLOAD(b0 + kk, &Bs[bb][o0]); GLOAD(b1 + kk, &Bs[bb][o1]);
        }
        const int buf = k & 3;
        bf16x8 af[4], bfv[4];
#pragma unroll
        for (int i = 0; i < 4; ++i)
            af[i] = *reinterpret_cast<const bf16x8*>(&As[buf][(size_t)(wr + i * 16 + lr) * 32 + lk]);
#pragma unroll
        for (int j = 0; j < 4; ++j)
            bfv[j] = *reinterpret_cast<const bf16x8*>(&Bs[buf][(size_t)(wc + j * 16 + lr) * 32 + lk]);
        __builtin_amdgcn_s_setprio(1);
#pragma unroll
        for (int i = 0; i < 4; ++i)
#pragma unroll
            for (int j = 0; j < 4; ++j)
                acc[i][j] = __builtin_amdgcn_mfma_f32_16x16x32_bf16(af[i], bfv[j], acc[i][j], 0, 0, 0);
        __builtin_amdgcn_s_setprio(0);
    }

#pragma unroll
    for (int j = 0; j < 4; ++j) {
        int col = n0 + wc + j * 16 + lr;
        float bv = BIAS ? bias[col] : 0.0f;
#pragma unroll
        for (int i = 0; i < 4; ++i) {
            int row = m0 + wr + i * 16 + (hi << 2);
#pragma unroll
            for (int r = 0; r < 4; ++r) {
                float v = acc[i][j][r] + bv;
                if (RELU) v = fmaxf(v, 0.0f);
                if (OUT_BF16)
                    ((unsigned short*)Cout)[(size_t)(row + r) * N + col] = f2bu(v);
                else
                    ((float*)Cout)[(size_t)(row + r) * N + col] = v;
            }
        }
    }
}

// ---------------- bf16 MFMA GEMM 64x64, BK=64, ring-4 counted vmcnt --------
// OUTMODE: 0 = f32 C, 1 = bf16 C, 2 = V-transpose direct to vt
template<bool BIAS, bool RELU, int OUTMODE>
__device__ __forceinline__ void gemm64_body(const __hip_bfloat16* __restrict__ A,
                                            const __hip_bfloat16* __restrict__ Bt,
                                            const float* __restrict__ bias,
                                            void* __restrict__ Cout,
                                            unsigned short* __restrict__ vtout,
                                            int K, float scale,
                                            __hip_bfloat16* As, __hip_bfloat16* Bs) {
    const int lb = blockIdx.x;
    const int wg = (lb & 7) * (gridDim.x >> 3) + (lb >> 3);
    const int m0 = (wg >> 3) * 64;
    const int n0 = (wg & 7) * 64;

    const int tid  = threadIdx.x;
    const int wave = tid >> 6;
    const int lane = tid & 63;
    const int lr   = lane & 15;
    const int hi   = lane >> 4;
    const int wr   = (wave >> 1) * 32;
    const int wc   = (wave & 1) * 32;

    f32x4 acc[2][2];
#pragma unroll
    for (int i = 0; i < 2; ++i)
#pragma unroll
        for (int j = 0; j < 2; ++j) acc[i][j] = (f32x4){0.f, 0.f, 0.f, 0.f};

    const int c0 = tid, c1 = tid + 256;
    const __hip_bfloat16* a0 = A  + (size_t)(m0 + (c0 >> 3)) * K + (((c0 & 7) ^ ((c0 >> 3) & 7)) << 3);
    const __hip_bfloat16* a1 = A  + (size_t)(m0 + (c1 >> 3)) * K + (((c1 & 7) ^ ((c1 >> 3) & 7)) << 3);
    const __hip_bfloat16* b0 = Bt + (size_t)(n0 + (c0 >> 3)) * K + (((c0 & 7) ^ ((c0 >> 3) & 7)) << 3);
    const __hip_bfloat16* b1 = Bt + (size_t)(n0 + (c1 >> 3)) * K + (((c1 & 7) ^ ((c1 >> 3) & 7)) << 3);
    const int o0 = wave * 512, o1 = 2048 + wave * 512;

    const int nst = K >> 6;
#pragma unroll
    for (int s = 0; s < 3; ++s) {
        if (s < nst) {
            GLOAD(a0 + s * 64, As + s * 4096 + o0); GLOAD(a1 + s * 64, As + s * 4096 + o1);
            GLOAD(b0 + s * 64, Bs + s * 4096 + o0); GLOAD(b1 + s * 64, Bs + s * 4096 + o1);
        }
    }

    for (int k = 0; k < nst; ++k) {
        const int ahead = (nst - 1 - k >= 2) ? 2 : (nst - 1 - k);
        waitv_ahead(ahead);
        hard_barrier();
        if (k + 3 < nst) {
            const int kk = (k + 3) << 6;
            const int bo = ((k + 3) & 3) * 4096;
            GLOAD(a0 + kk, As + bo + o0); GLOAD(a1 + kk, As + bo + o1);
            GLOAD(b0 + kk, Bs + bo + o0); GLOAD(b1 + kk, Bs + bo + o1);
        }
        const __hip_bfloat16* Ab = As + (k & 3) * 4096;
        const __hip_bfloat16* Bb = Bs + (k & 3) * 4096;
        __builtin_amdgcn_s_setprio(1);
#pragma unroll
        for (int ks = 0; ks < 2; ++ks) {
            bf16x8 af[2], bfv[2];
#pragma unroll
            for (int i = 0; i < 2; ++i) {
                int row = wr + i * 16 + lr;
                af[i] = *reinterpret_cast<const bf16x8*>(
                    &Ab[(size_t)row * 64 + (((ks * 4 + hi) ^ (row & 7)) << 3)]);
            }
#pragma unroll
            for (int j = 0; j < 2; ++j) {
                int row = wc + j * 16 + lr;
                bfv[j] = *reinterpret_cast<const bf16x8*>(
                    &Bb[(size_t)row * 64 + (((ks * 4 + hi) ^ (row & 7)) << 3)]);
            }
#pragma unroll
            for (int i = 0; i < 2; ++i)
#pragma unroll
                for (int j = 0; j < 2; ++j)
                    acc[i][j] = __builtin_amdgcn_mfma_f32_16x16x32_bf16(af[i], bfv[j], acc[i][j], 0, 0, 0);
        }
        __builtin_amdgcn_s_setprio(0);
    }

    if (OUTMODE == 2) {
        // transpose 64x64 tile in LDS, write directly into vt[bn*64+d][token]
        hard_barrier();                        // all ds_reads of As done
        unsigned short* T = (unsigned short*)As;
        const int TS = 68;
#pragma unroll
        for (int j = 0; j < 2; ++j)
#pragma unroll
            for (int i = 0; i < 2; ++i)
#pragma unroll
                for (int r = 0; r < 4; ++r)
                    T[(wr + i * 16 + (hi << 2) + r) * TS + wc + j * 16 + lr] =
                        f2bu(acc[i][j][r]);
        hard_barrier();
        const int b = tid >> 6, d = tid & 63;
        const int n = n0 >> 6, t0 = m0 >> 2;
        bf16x8 v0, v1;
#pragma unroll
        for (int e = 0; e < 8; ++e) {
            v0[e] = (short)T[((e) * 4 + b) * TS + d];
            v1[e] = (short)T[((e + 8) * 4 + b) * TS + d];
        }
        unsigned short* dst = vtout + ((size_t)((b * 8 + n) * 64 + d)) * 1024 + t0;
        *reinterpret_cast<bf16x8*>(dst) = v0;
        *reinterpret_cast<bf16x8*>(dst + 8) = v1;
        return;
    }

#pragma unroll
    for (int j = 0; j < 2; ++j) {
        int col = n0 + wc + j * 16 + lr;
        float bv = BIAS ? bias[col] : 0.0f;
#pragma unroll
        for (int i = 0; i < 2; ++i) {
            int row = m0 + wr + i * 16 + (hi << 2);
#pragma unroll
            for (int r = 0; r < 4; ++r) {
                float v = acc[i][j][r] * scale + bv;
                if (RELU) v = fmaxf(v, 0.0f);
                if (OUTMODE == 1)
                    ((unsigned short*)Cout)[(size_t)(row + r) * 512 + col] = f2bu(v);
                else
                    ((float*)Cout)[(size_t)(row + r) * 512 + col] = v;
            }
        }
    }
}

template<bool BIAS, bool RELU, bool OUT_BF16>
__global__ __launch_bounds__(256) void gemm64_k(const __hip_bfloat16* __restrict__ A,
                                                const __hip_bfloat16* __restrict__ Bt,
                                                const float* __restrict__ bias,
                                                void* __restrict__ Cout, int K) {
    __shared__ __hip_bfloat16 As[4 * 64 * 64];
    __shared__ __hip_bfloat16 Bs[4 * 64 * 64];
    gemm64_body<BIAS, RELU, OUT_BF16 ? 1 : 0>(A, Bt, bias, Cout, nullptr, K, 1.0f, As, Bs);
}

// QKV (+ fused prev-layer out_transpose on z==3):
// z=0 Q (scaled), z=1 K, z=2 V->vt direct, z=3 out_transpose(x, out, outl)
__global__ __launch_bounds__(256) void qkv_out_k(const __hip_bfloat16* __restrict__ A,
                                                 const __hip_bfloat16* __restrict__ B0,
                                                 const __hip_bfloat16* __restrict__ B1,
                                                 const __hip_bfloat16* __restrict__ B2,
                                                 __hip_bfloat16* __restrict__ C0,
                                                 __hip_bfloat16* __restrict__ C1,
                                                 unsigned short* __restrict__ vt,
                                                 const float* __restrict__ x,
                                                 float* __restrict__ out, int outl) {
    __shared__ __hip_bfloat16 As[4 * 64 * 64];
    __shared__ __hip_bfloat16 Bs[4 * 64 * 64];
    const int sel = blockIdx.z;
    if (sel == 3) {
        // out_transpose(l-1), LDS reused from As
        float (*tile)[65] = reinterpret_cast<float(*)[65]>(As);
        const int blk = blockIdx.x;          // 512 = t(16) x b(4) x dc(8)
        const int dc = blk & 7;
        const int b  = (blk >> 3) & 3;
        const int t  = blk >> 5;
        const int tid = threadIdx.x;
#pragma unroll
        for (int it = 0; it < 4; ++it) {
            int c = tid + it * 256;
            int hw = c >> 4, f4 = c & 15;
            const float* src = x + (size_t)((t * 64 + hw) * 4 + b) * 512 + dc * 64 + f4 * 4;
            float4 v = *reinterpret_cast<const float4*>(src);
            tile[hw][f4 * 4 + 0] = v.x; tile[hw][f4 * 4 + 1] = v.y;
            tile[hw][f4 * 4 + 2] = v.z; tile[hw][f4 * 4 + 3] = v.w;
        }
        __syncthreads();
        size_t ob = (((size_t)(b * 16 + t) * 4 + outl) * 512 + dc * 64) * 64;
#pragma unroll
        for (int it = 0; it < 4; ++it) {
            int c = tid + it * 256;
            int d = c >> 4, f4 = c & 15;
            float4 v = make_float4(tile[f4 * 4 + 0][d], tile[f4 * 4 + 1][d],
                                   tile[f4 * 4 + 2][d], tile[f4 * 4 + 3][d]);
            *reinterpret_cast<float4*>(out + ob + (size_t)d * 64 + f4 * 4) = v;
        }
        return;
    }
    if (sel == 2) {
        gemm64_body<false, false, 2>(A, B2, nullptr, nullptr, vt, 512, 1.0f, As, Bs);
    } else if (sel == 1) {
        gemm64_body<false, false, 1>(A, B1, nullptr, (void*)C1, nullptr, 512, 1.0f, As, Bs);
    } else {
        gemm64_body<false, false, 1>(A, B0, nullptr, (void*)C0, nullptr, 512, CSC, As, Bs);
    }
}

// ---------------- MFMA block-causal flash attention (flat softmax) ---------
__device__ __forceinline__ int aswz(int row, int col) {
    return (row * 64 + col) ^ ((row & 7) << 3);
}

__device__ __forceinline__ void stage_tile(const unsigned short* gbase, int stride,
                                           unsigned short* lds, int wave, int tid) {
#pragma unroll
    for (int it = 0; it < 2; ++it) {
        int c = tid + it * 256;
        int row = c >> 3;
        int i = (c & 7) ^ (row & 7);
        const unsigned short* g = gbase + (size_t)row * stride + i * 8;
        __builtin_amdgcn_global_load_lds(
            (const __attribute__((address_space(1))) void*)g,
            (__attribute__((address_space(3))) void*)(lds + it * 2048 + wave * 512),
            16, 0, 0);
    }
}

__global__ __launch_bounds__(256) void attn_mfma(const unsigned short* __restrict__ q,
                                                 const unsigned short* __restrict__ k,
                                                 const unsigned short* __restrict__ vt,
                                                 unsigned short* __restrict__ av) {
    __shared__ unsigned short Qs[64 * 64];
    __shared__ unsigned short Ks[4][64 * 64];
    __shared__ unsigned short Vts[4][64 * 64];
    __shared__ unsigned short Ps[64 * 64];

    const int tid = threadIdx.x;
    const int wave = tid >> 6, lane = tid & 63;
    const int lr = lane & 15, hi = lane >> 4;
    const int wr = wave * 16;

    const int p = blockIdx.x;            // XCD-affinity swizzle
    const int xcd = p & 7, idx = p >> 3;
    const int bn = xcd * 4 + (idx & 3);
    const int qb = 15 - (idx >> 2);      // long blocks first within XCD
    const int b = bn >> 3, n = bn & 7;

    const unsigned short* kcol  = k  + (size_t)b * 512 + n * 64;
    const unsigned short* vtrow = vt + (size_t)(bn * 64) * 1024;

    stage_tile(q + ((size_t)(qb * 64) * 4 + b) * 512 + n * 64, 2048, Qs, wave, tid);
    stage_tile(kcol, 2048, Ks[0], wave, tid);
    stage_tile(vtrow, 1024, Vts[0], wave, tid);
    if (qb >= 1) {
        stage_tile(kcol + (size_t)64 * 2048, 2048, Ks[1], wave, tid);
        stage_tile(vtrow + 64, 1024, Vts[1], wave, tid);
    }
    if (qb >= 2) {
        stage_tile(kcol + (size_t)128 * 2048, 2048, Ks[2], wave, tid);
        stage_tile(vtrow + 128, 1024, Vts[2], wave, tid);
    }

    f32x4 o_acc[4], l_acc;
#pragma unroll
    for (int db = 0; db < 4; ++db) o_acc[db] = (f32x4){0.f, 0.f, 0.f, 0.f};
    l_acc = (f32x4){0.f, 0.f, 0.f, 0.f};

    bf16x8 onesf;
#pragma unroll
    for (int e = 0; e < 8; ++e) onesf[e] = (short)0x3F80;   // bf16 1.0

    bf16x8 qf[2];

    for (int kb = 0; kb <= qb; ++kb) {
        const int ahead = (qb - kb >= 2) ? 2 : (qb - kb);
        waitv_ahead(ahead);
        hard_barrier();                  // stage(kb) fully in LDS for all waves
        if (kb + 3 <= qb) {
            stage_tile(kcol + (size_t)(kb + 3) * 64 * 2048, 2048,
                       Ks[(kb + 3) & 3], wave, tid);
            stage_tile(vtrow + (kb + 3) * 64, 1024, Vts[(kb + 3) & 3], wave, tid);
        }
        if (kb == 0) {
#pragma unroll
            for (int ks = 0; ks < 2; ++ks)
                qf[ks] = *reinterpret_cast<const bf16x8*>(
                    (const unsigned short*)Qs + aswz(wr + lr, ks * 32 + hi * 8));
        }
        const unsigned short* Kb = Ks[kb & 3];
        const unsigned short* Vb = Vts[kb & 3];

        f32x4 sf[4];
#pragma unroll
        for (int jb = 0; jb < 4; ++jb) sf[jb] = (f32x4){0.f, 0.f, 0.f, 0.f};
        __builtin_amdgcn_s_setprio(1);
#pragma unroll
        for (int ks = 0; ks < 2; ++ks) {
            bf16x8 a = qf[ks];
#pragma unroll
            for (int jb = 0; jb < 4; ++jb) {
                bf16x8 kf = *reinterpret_cast<const bf16x8*>(
                    Kb + aswz(jb * 16 + lr, ks * 32 + hi * 8));
                sf[jb] = __builtin_amdgcn_mfma_f32_16x16x32_bf16(a, kf, sf[jb], 0, 0, 0);
            }
        }
        __builtin_amdgcn_s_setprio(0);

        // flat softmax: p = exp2(min(s,100)); Q pre-scaled by 0.125*log2(e)
#pragma unroll
        for (int jb = 0; jb < 4; ++jb)
#pragma unroll
            for (int r = 0; r < 4; ++r) {
                float pe = exp2f(fminf(sf[jb][r], 100.0f));
                Ps[aswz(wr + 4 * hi + r, jb * 16 + lr)] = f2bu(pe);
            }
        WAITL0();
        hard_barrier();                  // P visible; vmcnt prefetch in flight

        __builtin_amdgcn_s_setprio(1);
#pragma unroll
        for (int ks = 0; ks < 2; ++ks) {
            bf16x8 pf = *reinterpret_cast<const bf16x8*>(
                (const unsigned short*)Ps + aswz(wr + lr, ks * 32 + hi * 8));
            l_acc = __builtin_amdgcn_mfma_f32_16x16x32_bf16(pf, onesf, l_acc, 0, 0, 0);
#pragma unroll
            for (int db = 0; db < 4; ++db) {
                bf16x8 vf = *reinterpret_cast<const bf16x8*>(
                    Vb + aswz(db * 16 + lr, ks * 32 + hi * 8));
                o_acc[db] = __builtin_amdgcn_mfma_f32_16x16x32_bf16(pf, vf, o_acc[db], 0, 0, 0);
            }
        }
        __builtin_amdgcn_s_setprio(0);
    }

#pragma unroll
    for (int r = 0; r < 4; ++r) {
        float inv = 1.0f / l_acc[r];
        int row = qb * 64 + wr + 4 * hi + r;
#pragma unroll
        for (int db = 0; db < 4; ++db)
            av[((size_t)row * 4 + b) * 512 + n * 64 + db * 16 + lr] =
                f2bu(o_acc[db][r] * inv);
    }
}

// ---------------- LN(y)*g+b + x -> x (f32 + bf16) ------
__global__ __launch_bounds__(64) void add_ln_kernel(const float* __restrict__ y,
                                                    const float* __restrict__ g,
                                                    const float* __restrict__ bta,
                                                    float* __restrict__ x,
                                                    __hip_bfloat16* __restrict__ x_bf) {
    const int row = blockIdx.x;     // 0..4095
    const int tid = threadIdx.x;    // 0..63
    const float* yr = y + (size_t)row * DD;
    float4 v0 = *reinterpret_cast<const float4*>(&yr[tid * 4]);
    float4 v1 = *reinterpret_cast<const float4*>(&yr[256 + tid * 4]);
    float s = v0.x + v0.y + v0.z + v0.w + v1.x + v1.y + v1.z + v1.w;
    float ss = v0.x * v0.x + v0.y * v0.y + v0.z * v0.z + v0.w * v0.w +
               v1.x * v1.x + v1.y * v1.y + v1.z * v1.z + v1.w * v1.w;
#pragma unroll
    for (int off = 32; off; off >>= 1) {
        s  += __shfl_xor(s, off);
        ss += __shfl_xor(ss, off);
    }
    float mean = s * (1.0f / 512.0f);
    float var = ss * (1.0f / 512.0f) - mean * mean;
    float rstd = rsqrtf(var + EPS);

    float* xr = x + (size_t)row * DD;
    float vals[8] = {v0.x, v0.y, v0.z, v0.w, v1.x, v1.y, v1.z, v1.w};
#pragma unroll
    for (int e = 0; e < 8; ++e) {
        int d = (e < 4) ? (tid * 4 + e) : (256 + tid * 4 + (e - 4));
        float nrm = (vals[e] - mean) * rstd * g[d] + bta[d];
        float xo = xr[d] + nrm;
        xr[d] = xo;
        x_bf[(size_t)row * DD + d] = __float2bfloat16(xo);
    }
}

// ---------------- coalesced layer-output transpose (final layer) -----------
__global__ __launch_bounds__(256) void out_transpose(const float* __restrict__ x,
                                                     float* __restrict__ out, int l) {
    __shared__ float tile[64][65];
    const int blk = blockIdx.x;          // 512 = t(16) * b(4) * dc(8)
    const int dc = blk & 7;
    const int b  = (blk >> 3) & 3;
    const int t  = blk >> 5;
    const int tid = threadIdx.x;
#pragma unroll
    for (int it = 0; it < 4; ++it) {
        int c = tid + it * 256;          // 0..1023
        int hw = c >> 4, f4 = c & 15;
        const float* src = x + (size_t)((t * 64 + hw) * 4 + b) * 512 + dc * 64 + f4 * 4;
        float4 v = *reinterpret_cast<const float4*>(src);
        tile[hw][f4 * 4 + 0] = v.x; tile[hw][f4 * 4 + 1] = v.y;
        tile[hw][f4 * 4 + 2] = v.z; tile[hw][f4 * 4 + 3] = v.w;
    }
    __syncthreads();
    size_t ob = (((size_t)(b * 16 + t) * 4 + l) * 512 + dc * 64) * 64;
#pragma unroll
    for (int it = 0; it < 4; ++it) {
        int c = tid + it * 256;
        int d = c >> 4, f4 = c & 15;
        float4 v = make_float4(tile[f4 * 4 + 0][d], tile[f4 * 4 + 1][d],
                               tile[f4 * 4 + 2][d], tile[f4 * 4 + 3][d]);
        *reinterpret_cast<float4*>(out + ob + (size_t)d * 64 + f4 * 4) = v;
    }
}

// ---------------- launcher ----------------
extern "C" void kernel_launch(void* const* d_in, const int* in_sizes, int n_in,
                              void* d_out, int out_size, void* d_ws, size_t ws_size,
                              hipStream_t stream) {
    const float* z    = (const float*)d_in[0];
    const float* Wq   = (const float*)d_in[1];
    const float* Wk   = (const float*)d_in[2];
    const float* Wv   = (const float*)d_in[3];
    const float* Wo   = (const float*)d_in[4];
    const float* W1   = (const float*)d_in[5];
    const float* b1   = (const float*)d_in[6];
    const float* W2   = (const float*)d_in[7];
    const float* b2   = (const float*)d_in[8];
    const float* ln1g = (const float*)d_in[9];
    const float* ln1b = (const float*)d_in[10];
    const float* ln2g = (const float*)d_in[11];
    const float* ln2b = (const float*)d_in[12];
    float* out = (float*)d_out;

    const size_t MB = 1u << 20;
    char* base = (char*)d_ws;
    float*          x     = (float*)(base);                       // 8 MB
    __hip_bfloat16* x_bf  = (__hip_bfloat16*)(base + 8  * MB);    // 4 MB
    __hip_bfloat16* q_bf  = (__hip_bfloat16*)(base + 12 * MB);    // 4 MB
    __hip_bfloat16* k_bf  = (__hip_bfloat16*)(base + 16 * MB);    // 4 MB
    __hip_bfloat16* av_bf = (__hip_bfloat16*)(base + 24 * MB);    // 4 MB
    float*          tmp   = (float*)(base + 28 * MB);             // 8 MB
    __hip_bfloat16* wall  = (__hip_bfloat16*)(base + 36 * MB);    // 24 MB (4 layers)
    __hip_bfloat16* ff1_bf = q_bf;               // aliases q (dead after attn)
    unsigned short* vt    = (unsigned short*)(base + 20 * MB);    // 4 MB (old v slot)

    const size_t WL = 4 * 512 * 512 + 2 * 512 * 2048;   // per-layer weight elems

    embed_kernel<<<512, 256, 0, stream>>>(z, x, x_bf);
    wt_convert<<<dim3(3072, 4), 256, 0, stream>>>(Wq, Wk, Wv, Wo, W1, W2, wall);

    for (int l = 0; l < 4; ++l) {
        __hip_bfloat16* wl  = wall + (size_t)l * WL;
        __hip_bfloat16* wqt = wl;
        __hip_bfloat16* wkt = wqt + 512 * 512;
        __hip_bfloat16* wvt = wkt + 512 * 512;
        __hip_bfloat16* wot = wvt + 512 * 512;
        __hip_bfloat16* w1t = wot + 512 * 512;     // [2048][512]
        __hip_bfloat16* w2t = w1t + 512 * 2048;    // [512][2048]

        // QKV (+ fused out_transpose of layer l-1 on z=3)
        qkv_out_k<<<dim3(512, 1, l == 0 ? 3 : 4), 256, 0, stream>>>(
            x_bf, wqt, wkt, wvt, q_bf, k_bf, vt, x, out, l - 1);

        attn_mfma<<<512, 256, 0, stream>>>(
            (const unsigned short*)q_bf, (const unsigned short*)k_bf,
            vt, (unsigned short*)av_bf);

        gemm64_k<false, false, false><<<512, 256, 0, stream>>>(
            av_bf, wot, nullptr, (void*)tmp, 512);
        add_ln_kernel<<<MROWS, 64, 0, stream>>>(tmp, ln1g + l * 512, ln1b + l * 512,
                                                x, x_bf);

        gemm_k<true, true, true><<<512, 256, 0, stream>>>(
            x_bf, w1t, b1 + l * 2048, (void*)ff1_bf, 2048, 512, 16);
        gemm64_k<true, false, false><<<512, 256, 0, stream>>>(
            ff1_bf, w2t, b2 + l * 512, (void*)tmp, 2048);
        add_ln_kernel<<<MROWS, 64, 0, stream>>>(tmp, ln2g + l * 512, ln2b + l * 512,
                                                x, x_bf);
    }
    out_transpose<<<512, 256, 0, stream>>>(x, out, 3);
}